// Round 3
// baseline (189.809 us; speedup 1.0000x reference)
//
#include <hip/hip_runtime.h>
#include <stdint.h>

typedef __bf16 bf16x8 __attribute__((ext_vector_type(8)));
typedef __bf16 bf16x4 __attribute__((ext_vector_type(4)));
typedef short short4s __attribute__((ext_vector_type(4)));
typedef float f32x4 __attribute__((ext_vector_type(4)));

#define PSCALE (0.125f / 2048.0f)

// async global->LDS, 16B per lane. LDS dest must be wave-uniform; HW adds lane*16.
#define GLOAD16(src, dst)                                                      \
  __builtin_amdgcn_global_load_lds(                                            \
      (__attribute__((address_space(1))) void*)const_cast<__bf16*>(src),       \
      (__attribute__((address_space(3))) void*)(dst), 16, 0, 0)

// ---------------- LayerNorm + cast to bf16 ----------------
__global__ __launch_bounds__(256) void ln_fused(const float* __restrict__ x,
                                                const float* __restrict__ w,
                                                const float* __restrict__ b,
                                                __bf16* __restrict__ xn) {
  const int row = blockIdx.x;           // 8192 rows
  const int t = threadIdx.x;            // 256 threads, 4 floats each
  const float4 v = ((const float4*)(x + (size_t)row * 1024))[t];
  float s = v.x + v.y + v.z + v.w;
  float ss = v.x * v.x + v.y * v.y + v.z * v.z + v.w * v.w;
#pragma unroll
  for (int o = 32; o; o >>= 1) {
    s += __shfl_down(s, o);
    ss += __shfl_down(ss, o);
  }
  __shared__ float red[8];
  if ((t & 63) == 0) {
    red[t >> 6] = s;
    red[4 + (t >> 6)] = ss;
  }
  __syncthreads();
  const float tot = red[0] + red[1] + red[2] + red[3];
  const float tot2 = red[4] + red[5] + red[6] + red[7];
  const float mu = tot * (1.0f / 1024.0f);
  const float var = tot2 * (1.0f / 1024.0f) - mu * mu;
  const float rs = rsqrtf(var + 1e-5f);
  const float4 wv = ((const float4*)w)[t];
  const float4 bv = ((const float4*)b)[t];
  bf16x4 o;
  o[0] = (__bf16)((v.x - mu) * rs * wv.x + bv.x);
  o[1] = (__bf16)((v.y - mu) * rs * wv.y + bv.y);
  o[2] = (__bf16)((v.z - mu) * rs * wv.z + bv.z);
  o[3] = (__bf16)((v.w - mu) * rs * wv.w + bv.w);
  ((bf16x4*)xn)[(size_t)row * 256 + t] = o;
}

// -------- transpose + fp32->bf16: A[R][C] -> At[C][R] (64x64 tiles) --------
__global__ __launch_bounds__(256) void transpose_cvt(const float* __restrict__ A,
                                                     __bf16* __restrict__ At,
                                                     int R, int C) {
  __shared__ __bf16 T[64][72];
  const int rb = blockIdx.y * 64, cb = blockIdx.x * 64;
  const int tid = threadIdx.x;
  const int r = tid >> 2, cg = tid & 3;
#pragma unroll
  for (int k = 0; k < 4; ++k) {
    const float4 v =
        *(const float4*)(A + (size_t)(rb + r) * C + cb + cg * 16 + k * 4);
    T[cg * 16 + k * 4 + 0][r] = (__bf16)v.x;
    T[cg * 16 + k * 4 + 1][r] = (__bf16)v.y;
    T[cg * 16 + k * 4 + 2][r] = (__bf16)v.z;
    T[cg * 16 + k * 4 + 3][r] = (__bf16)v.w;
  }
  __syncthreads();
#pragma unroll
  for (int i = 0; i < 2; ++i) {
    const int j = i * 256 + tid;
    const int c = j >> 3, s8 = j & 7;
    const bf16x8 o = *(const bf16x8*)&T[c][s8 * 8];
    *(bf16x8*)(At + (size_t)(cb + c) * R + rb + s8 * 8) = o;
  }
}

// ---- stage a [128 rows][64 k] bf16 tile into LDS, swizzled source (G4/rule21)
// LDS linear chunk j = row*8 + slot holds global k-chunk (slot ^ (row&7)).
__device__ __forceinline__ void stage_128x64(const __bf16* __restrict__ g,
                                             int ld, __bf16* lds) {
  const int lane = threadIdx.x & 63, w = threadIdx.x >> 6;
#pragma unroll
  for (int i = 0; i < 4; ++i) {
    const int j = i * 256 + w * 64 + lane;  // 1024 chunks of 16B
    const int row = j >> 3, slot = j & 7;
    const __bf16* src = g + (size_t)row * ld + ((slot ^ (row & 7)) << 3);
    GLOAD16(src, lds + (size_t)(i * 256 + w * 64) * 8);
  }
}

// ---- stage Vt tile [64 d][128 keys] (global row stride 2048) ----
// Full 4-bit XOR: LDS chunk (d, slot) of 16B holds global key-chunk
// (slot ^ (d & 15)) -> a 16-lane group reading chunk c across rows d..d+15
// hits 16 distinct slots = conflict-free.
__device__ __forceinline__ void stage_vt(const __bf16* __restrict__ g,
                                         __bf16* lds) {
  const int lane = threadIdx.x & 63, w = threadIdx.x >> 6;
#pragma unroll
  for (int i = 0; i < 4; ++i) {
    const int j = i * 256 + w * 64 + lane;  // 1024 chunks of 16B (16 per d-row)
    const int d = j >> 4, slot = j & 15;
    const __bf16* src = g + (size_t)d * 2048 + ((slot ^ (d & 15)) << 3);
    GLOAD16(src, lds + (size_t)(i * 256 + w * 64) * 8);
  }
}

// ---------------- NT-GEMM: C[M][N] = A[M][K] * B[N][K]^T ----------------
// 128x128 tile, BK=64, 4 waves of 64x64. MODE 0: QKV split epilogue
// (Q pre-scaled by PSCALE so attn needs no per-element scaling).
// MODE 1: fp32 out + bias.
template <int MODE>
__global__ __launch_bounds__(256) void gemm_nt(
    const __bf16* __restrict__ A, const __bf16* __restrict__ B, int K,
    float* __restrict__ outF, __bf16* __restrict__ Qo, __bf16* __restrict__ Ko,
    __bf16* __restrict__ Vto, const float* __restrict__ bias) {
  __shared__ __bf16 As[128 * 64];
  __shared__ __bf16 Bs[128 * 64];
  const int lane = threadIdx.x & 63, w = threadIdx.x >> 6;
  const int rb = blockIdx.y * 128, cb = blockIdx.x * 128;
  const int wr = (w >> 1) * 64, wc = (w & 1) * 64;
  f32x4 acc[4][4] = {};
  const __bf16* Ab = A + (size_t)rb * K;
  const __bf16* Bb = B + (size_t)cb * K;
  const int nkb = K >> 6;
  for (int kb = 0; kb < nkb; ++kb) {
    stage_128x64(Ab + kb * 64, K, As);
    stage_128x64(Bb + kb * 64, K, Bs);
    __syncthreads();
#pragma unroll
    for (int ks = 0; ks < 2; ++ks) {
      bf16x8 af[4], bfr[4];
      const int kc = ks * 4 + (lane >> 4);
#pragma unroll
      for (int rt = 0; rt < 4; ++rt) {
        const int lr = wr + rt * 16 + (lane & 15);
        af[rt] = *(const bf16x8*)(As + lr * 64 + ((kc ^ (lr & 7)) << 3));
      }
#pragma unroll
      for (int ct = 0; ct < 4; ++ct) {
        const int lc = wc + ct * 16 + (lane & 15);
        bfr[ct] = *(const bf16x8*)(Bs + lc * 64 + ((kc ^ (lc & 7)) << 3));
      }
#pragma unroll
      for (int rt = 0; rt < 4; ++rt)
#pragma unroll
        for (int ct = 0; ct < 4; ++ct)
          acc[rt][ct] = __builtin_amdgcn_mfma_f32_16x16x32_bf16(
              af[rt], bfr[ct], acc[rt][ct], 0, 0, 0);
    }
    __syncthreads();
  }
  // epilogue: C row = rb+wr+rt*16+(lane>>4)*4+r, col = cb+wc+ct*16+(lane&15)
  const int r0 = rb + wr + (lane >> 4) * 4;
  if (MODE == 1) {
#pragma unroll
    for (int ct = 0; ct < 4; ++ct) {
      const int col = cb + wc + ct * 16 + (lane & 15);
      const float bv = bias[col];
#pragma unroll
      for (int rt = 0; rt < 4; ++rt) {
        const int row = r0 + rt * 16;
#pragma unroll
        for (int r = 0; r < 4; ++r)
          outF[(size_t)(row + r) * 1024 + col] = acc[rt][ct][r] + bv;
      }
    }
  } else {
#pragma unroll
    for (int ct = 0; ct < 4; ++ct) {
      const int col = cb + wc + ct * 16 + (lane & 15);  // 0..3071
      const int part = col >> 10, rem = col & 1023;
      const int h = rem >> 6, d = rem & 63;
#pragma unroll
      for (int rt = 0; rt < 4; ++rt) {
        const int row = r0 + rt * 16;  // 0..8191
        const int bi = row >> 11, n = row & 2047;
        const size_t bh = (size_t)bi * 16 + h;
        if (part == 2) {  // V stored transposed: Vt[bh][d][n]
          bf16x4 pv;
#pragma unroll
          for (int r = 0; r < 4; ++r) pv[r] = (__bf16)acc[rt][ct][r];
          *(bf16x4*)(Vto + (bh * 64 + d) * 2048 + n) = pv;
        } else if (part == 0) {  // Q: [bh][n][d], pre-scaled by PSCALE
          __bf16* dst = Qo + (bh * 2048 + n) * 64 + d;
#pragma unroll
          for (int r = 0; r < 4; ++r)
            dst[(size_t)r * 64] = (__bf16)(acc[rt][ct][r] * PSCALE);
        } else {  // K: [bh][n][d]
          __bf16* dst = Ko + (bh * 2048 + n) * 64 + d;
#pragma unroll
          for (int r = 0; r < 4; ++r) dst[(size_t)r * 64] = (__bf16)acc[rt][ct][r];
        }
      }
    }
  }
}

// ------------- fused relu-attention: O = relu(Q' K^T) @ V  (Q' pre-scaled) --
// v3: 256-q blocks, 4 waves x 64 q each (K/V LDS reads amortized over 2x q),
// double-buffered K/V tiles with counted vmcnt(8) (T3/T4 2-phase pipeline),
// raw s_barriers (never drain vmcnt to 0 mid-loop). Swapped QK^T keeps P in
// registers: lane holds P[q=c15][4 keys] == A-frag of mfma_f32_16x16x16bf16.
// grid (x=bh, y=qb): XCD = bh%8 -> each XCD's K/V working set = 8bh*0.5MB
// = 4MB = its L2.
__global__ __launch_bounds__(256) void attn_relu(
    const __bf16* __restrict__ Q, const __bf16* __restrict__ K,
    const __bf16* __restrict__ Vt, __bf16* __restrict__ O) {
  __shared__ __bf16 Ks[2][128 * 64];   // 2 x 16 KB
  __shared__ __bf16 Vs[2][64 * 128];   // 2 x 16 KB
  const int lane = threadIdx.x & 63, w = threadIdx.x >> 6;
  const int g = lane >> 4, c15 = lane & 15;
  const int bh = blockIdx.x, qb = blockIdx.y;
  const __bf16* Qg = Q + ((size_t)bh * 2048 + qb * 256) * 64;
  const __bf16* Kg = K + (size_t)bh * 2048 * 64;
  const __bf16* Vg = Vt + (size_t)bh * 64 * 2048;

  bf16x8 qf[4][2];  // wave's 64 q-rows as B-fragments (col=q=lane&15)
#pragma unroll
  for (int rt = 0; rt < 4; ++rt)
#pragma unroll
    for (int ks = 0; ks < 2; ++ks) {
      const int row = w * 64 + rt * 16 + c15;
      qf[rt][ks] = *(const bf16x8*)(Qg + row * 64 + ks * 32 + (g << 3));
    }
  f32x4 oacc[4][4] = {};

  // prologue: stage tile 0 into buffer 0 (8 gload_lds per thread per tile)
  stage_128x64(Kg, 64, Ks[0]);
  stage_vt(Vg, Vs[0]);

  for (int kb = 0; kb < 16; ++kb) {
    const int cur = kb & 1;
    if (kb < 15) {
      stage_128x64(Kg + (size_t)(kb + 1) * 128 * 64, 64, Ks[cur ^ 1]);
      stage_vt(Vg + (kb + 1) * 128, Vs[cur ^ 1]);
      // 16 outstanding (cur 8 + nxt 8) -> wait for the 8 oldest (= cur tile)
      asm volatile("s_waitcnt vmcnt(8)" ::: "memory");
    } else {
      asm volatile("s_waitcnt vmcnt(0)" ::: "memory");
    }
    __builtin_amdgcn_s_barrier();  // cur tile staged for all waves
    const __bf16* __restrict__ Kc = Ks[cur];
    const __bf16* __restrict__ Vc = Vs[cur];
#pragma unroll
    for (int ct = 0; ct < 8; ++ct) {
      // S^T[key][q] for 16 keys x 64 q (this wave)
      const int kr = ct * 16 + c15;
      const bf16x8 kf0 = *(const bf16x8*)(Kc + kr * 64 + ((g ^ (kr & 7)) << 3));
      const bf16x8 kf1 =
          *(const bf16x8*)(Kc + kr * 64 + (((4 + g) ^ (kr & 7)) << 3));
      f32x4 s[4] = {{}, {}, {}, {}};
#pragma unroll
      for (int rt = 0; rt < 4; ++rt) {
        s[rt] = __builtin_amdgcn_mfma_f32_16x16x32_bf16(kf0, qf[rt][0], s[rt],
                                                        0, 0, 0);
        s[rt] = __builtin_amdgcn_mfma_f32_16x16x32_bf16(kf1, qf[rt][1], s[rt],
                                                        0, 0, 0);
      }
      // relu -> bf16; lane holds P[q=c15][keys ct*16+4g .. +4] = PV A-frag
      short4s pa[4];
#pragma unroll
      for (int rt = 0; rt < 4; ++rt) {
        bf16x4 p;
#pragma unroll
        for (int r = 0; r < 4; ++r) p[r] = (__bf16)fmaxf(s[rt][r], 0.0f);
        pa[rt] = __builtin_bit_cast(short4s, p);
      }
      const int vchunk = 2 * ct + (g >> 1);  // 16B chunk index of keys
#pragma unroll
      for (int dt = 0; dt < 4; ++dt) {
        const int d = dt * 16 + c15;
        const bf16x4 vfr = *(const bf16x4*)(
            Vc + d * 128 + (((vchunk ^ c15) << 3) + 4 * (g & 1)));
        const short4s vb = __builtin_bit_cast(short4s, vfr);
#pragma unroll
        for (int rt = 0; rt < 4; ++rt)
          oacc[rt][dt] = __builtin_amdgcn_mfma_f32_16x16x16bf16_1k(
              pa[rt], vb, oacc[rt][dt], 0, 0, 0);
      }
    }
    __builtin_amdgcn_s_barrier();  // all waves done reading cur before restage
  }
  // write O merged-head: [b][n][h*64+d] bf16
  const int bi = bh >> 4, h = bh & 15;
#pragma unroll
  for (int rt = 0; rt < 4; ++rt)
#pragma unroll
    for (int dt = 0; dt < 4; ++dt) {
      const int col = h * 64 + dt * 16 + c15;
      const int n0 = qb * 256 + w * 64 + rt * 16 + g * 4;
      __bf16* dst = O + ((size_t)bi * 2048 + n0) * 1024 + col;
#pragma unroll
      for (int r = 0; r < 4; ++r) dst[(size_t)r * 1024] = (__bf16)oacc[rt][dt][r];
    }
}

extern "C" void kernel_launch(void* const* d_in, const int* in_sizes, int n_in,
                              void* d_out, int out_size, void* d_ws,
                              size_t ws_size, hipStream_t stream) {
  (void)in_sizes; (void)n_in; (void)out_size; (void)ws_size;
  const float* x = (const float*)d_in[0];
  const float* ln_w = (const float*)d_in[1];
  const float* ln_b = (const float*)d_in[2];
  const float* w_qkv = (const float*)d_in[3];
  const float* w_out = (const float*)d_in[4];
  const float* b_out = (const float*)d_in[5];
  // d_in[6] = layer_index == 2 (< DEPTH/2) -> relu branch only.
  char* ws = (char*)d_ws;
  __bf16* xn = (__bf16*)(ws);                           // 16 MB
  __bf16* Wt1 = (__bf16*)(ws + (size_t)(16u << 20));    // 6 MB  [3072][1024]
  __bf16* Wt2 = (__bf16*)(ws + (size_t)(22u << 20));    // 2 MB  [1024][1024]
  __bf16* Qb = (__bf16*)(ws + (size_t)(24u << 20));     // 16 MB [64][2048][64]
  __bf16* Kb = (__bf16*)(ws + (size_t)(40u << 20));     // 16 MB
  __bf16* Vtb = (__bf16*)(ws + (size_t)(56u << 20));    // 16 MB [64][64][2048]
  __bf16* Ob = (__bf16*)(ws + (size_t)(72u << 20));     // 16 MB [8192][1024]
  float* out = (float*)d_out;

  ln_fused<<<8192, 256, 0, stream>>>(x, ln_w, ln_b, xn);
  transpose_cvt<<<dim3(48, 16), 256, 0, stream>>>(w_qkv, Wt1, 1024, 3072);
  transpose_cvt<<<dim3(16, 16), 256, 0, stream>>>(w_out, Wt2, 1024, 1024);
  gemm_nt<0><<<dim3(24, 64), 256, 0, stream>>>(xn, Wt1, 1024, nullptr, Qb, Kb,
                                               Vtb, nullptr);
  attn_relu<<<dim3(64, 8), 256, 0, stream>>>(Qb, Kb, Vtb, Ob);
  gemm_nt<1><<<dim3(8, 64), 256, 0, stream>>>(Ob, Wt2, 1024, out, nullptr,
                                              nullptr, nullptr, b_out);
}

// Round 4
// 175.622 us; speedup vs baseline: 1.0808x; 1.0808x over previous
//
#include <hip/hip_runtime.h>
#include <stdint.h>

typedef __bf16 bf16x8 __attribute__((ext_vector_type(8)));
typedef __bf16 bf16x4 __attribute__((ext_vector_type(4)));
typedef float f32x4 __attribute__((ext_vector_type(4)));

#define PSCALE (0.125f / 2048.0f)

// async global->LDS, 16B per lane. LDS dest must be wave-uniform; HW adds lane*16.
#define GLOAD16(src, dst)                                                      \
  __builtin_amdgcn_global_load_lds(                                            \
      (__attribute__((address_space(1))) void*)const_cast<__bf16*>(src),       \
      (__attribute__((address_space(3))) void*)(dst), 16, 0, 0)

// ---------------- LayerNorm + cast to bf16 ----------------
__global__ __launch_bounds__(256) void ln_fused(const float* __restrict__ x,
                                                const float* __restrict__ w,
                                                const float* __restrict__ b,
                                                __bf16* __restrict__ xn) {
  const int row = blockIdx.x;           // 8192 rows
  const int t = threadIdx.x;            // 256 threads, 4 floats each
  const float4 v = ((const float4*)(x + (size_t)row * 1024))[t];
  float s = v.x + v.y + v.z + v.w;
  float ss = v.x * v.x + v.y * v.y + v.z * v.z + v.w * v.w;
#pragma unroll
  for (int o = 32; o; o >>= 1) {
    s += __shfl_down(s, o);
    ss += __shfl_down(ss, o);
  }
  __shared__ float red[8];
  if ((t & 63) == 0) {
    red[t >> 6] = s;
    red[4 + (t >> 6)] = ss;
  }
  __syncthreads();
  const float tot = red[0] + red[1] + red[2] + red[3];
  const float tot2 = red[4] + red[5] + red[6] + red[7];
  const float mu = tot * (1.0f / 1024.0f);
  const float var = tot2 * (1.0f / 1024.0f) - mu * mu;
  const float rs = rsqrtf(var + 1e-5f);
  const float4 wv = ((const float4*)w)[t];
  const float4 bv = ((const float4*)b)[t];
  bf16x4 o;
  o[0] = (__bf16)((v.x - mu) * rs * wv.x + bv.x);
  o[1] = (__bf16)((v.y - mu) * rs * wv.y + bv.y);
  o[2] = (__bf16)((v.z - mu) * rs * wv.z + bv.z);
  o[3] = (__bf16)((v.w - mu) * rs * wv.w + bv.w);
  ((bf16x4*)xn)[(size_t)row * 256 + t] = o;
}

// -------- transpose + fp32->bf16: A[R][C] -> At[C][R] (64x64 tiles) --------
__global__ __launch_bounds__(256) void transpose_cvt(const float* __restrict__ A,
                                                     __bf16* __restrict__ At,
                                                     int R, int C) {
  __shared__ __bf16 T[64][72];
  const int rb = blockIdx.y * 64, cb = blockIdx.x * 64;
  const int tid = threadIdx.x;
  const int r = tid >> 2, cg = tid & 3;
#pragma unroll
  for (int k = 0; k < 4; ++k) {
    const float4 v =
        *(const float4*)(A + (size_t)(rb + r) * C + cb + cg * 16 + k * 4);
    T[cg * 16 + k * 4 + 0][r] = (__bf16)v.x;
    T[cg * 16 + k * 4 + 1][r] = (__bf16)v.y;
    T[cg * 16 + k * 4 + 2][r] = (__bf16)v.z;
    T[cg * 16 + k * 4 + 3][r] = (__bf16)v.w;
  }
  __syncthreads();
#pragma unroll
  for (int i = 0; i < 2; ++i) {
    const int j = i * 256 + tid;
    const int c = j >> 3, s8 = j & 7;
    const bf16x8 o = *(const bf16x8*)&T[c][s8 * 8];
    *(bf16x8*)(At + (size_t)(cb + c) * R + rb + s8 * 8) = o;
  }
}

// ---- stage a [128 rows][64 k] bf16 tile into LDS, swizzled source (G4/rule21)
// LDS linear chunk j = row*8 + slot holds global k-chunk (slot ^ (row&7)).
__device__ __forceinline__ void stage_128x64(const __bf16* __restrict__ g,
                                             int ld, __bf16* lds) {
  const int lane = threadIdx.x & 63, w = threadIdx.x >> 6;
#pragma unroll
  for (int i = 0; i < 4; ++i) {
    const int j = i * 256 + w * 64 + lane;  // 1024 chunks of 16B
    const int row = j >> 3, slot = j & 7;
    const __bf16* src = g + (size_t)row * ld + ((slot ^ (row & 7)) << 3);
    GLOAD16(src, lds + (size_t)(i * 256 + w * 64) * 8);
  }
}

// ---- stage K tile [128 keys][64 d] with bit-permuted rows: LDS row `row`
// holds global key kappa(row), kappa: b4b3b2 <- b3b2b4 (bijective). With this,
// the two QK^T MFMAs of each 32-key group leave lane g holding keys
// 32u+8g+0..7 == the A-fragment k-order of mfma_f32_16x16x32_bf16 (K=32 PV).
__device__ __forceinline__ void stage_k_perm(const __bf16* __restrict__ g,
                                             __bf16* lds) {
  const int lane = threadIdx.x & 63, w = threadIdx.x >> 6;
#pragma unroll
  for (int i = 0; i < 4; ++i) {
    const int j = i * 256 + w * 64 + lane;  // 1024 chunks of 16B
    const int row = j >> 3, slot = j & 7;
    const int srcrow =
        (row & 96) | ((row & 12) << 1) | ((row & 16) >> 2) | (row & 3);
    const __bf16* src = g + (size_t)srcrow * 64 + ((slot ^ (row & 7)) << 3);
    GLOAD16(src, lds + (size_t)(i * 256 + w * 64) * 8);
  }
}

// ---- stage Vt tile [64 d][128 keys] (global row stride 2048) ----
// Full 4-bit XOR: LDS chunk (d, slot) holds global key-chunk (slot ^ (d&15)).
__device__ __forceinline__ void stage_vt(const __bf16* __restrict__ g,
                                         __bf16* lds) {
  const int lane = threadIdx.x & 63, w = threadIdx.x >> 6;
#pragma unroll
  for (int i = 0; i < 4; ++i) {
    const int j = i * 256 + w * 64 + lane;  // 1024 chunks of 16B (16 per d-row)
    const int d = j >> 4, slot = j & 15;
    const __bf16* src = g + (size_t)d * 2048 + ((slot ^ (d & 15)) << 3);
    GLOAD16(src, lds + (size_t)(i * 256 + w * 64) * 8);
  }
}

// ---------------- NT-GEMM: C[M][N] = A[M][K] * B[N][K]^T ----------------
// 128x128 tile, BK=64, 4 waves of 64x64. MODE 0: QKV split epilogue
// (Q pre-scaled by PSCALE so attn needs no per-element scaling).
// MODE 1: fp32 out + bias.
template <int MODE>
__global__ __launch_bounds__(256) void gemm_nt(
    const __bf16* __restrict__ A, const __bf16* __restrict__ B, int K,
    float* __restrict__ outF, __bf16* __restrict__ Qo, __bf16* __restrict__ Ko,
    __bf16* __restrict__ Vto, const float* __restrict__ bias) {
  __shared__ __bf16 As[128 * 64];
  __shared__ __bf16 Bs[128 * 64];
  const int lane = threadIdx.x & 63, w = threadIdx.x >> 6;
  const int rb = blockIdx.y * 128, cb = blockIdx.x * 128;
  const int wr = (w >> 1) * 64, wc = (w & 1) * 64;
  f32x4 acc[4][4] = {};
  const __bf16* Ab = A + (size_t)rb * K;
  const __bf16* Bb = B + (size_t)cb * K;
  const int nkb = K >> 6;
  for (int kb = 0; kb < nkb; ++kb) {
    stage_128x64(Ab + kb * 64, K, As);
    stage_128x64(Bb + kb * 64, K, Bs);
    __syncthreads();
#pragma unroll
    for (int ks = 0; ks < 2; ++ks) {
      bf16x8 af[4], bfr[4];
      const int kc = ks * 4 + (lane >> 4);
#pragma unroll
      for (int rt = 0; rt < 4; ++rt) {
        const int lr = wr + rt * 16 + (lane & 15);
        af[rt] = *(const bf16x8*)(As + lr * 64 + ((kc ^ (lr & 7)) << 3));
      }
#pragma unroll
      for (int ct = 0; ct < 4; ++ct) {
        const int lc = wc + ct * 16 + (lane & 15);
        bfr[ct] = *(const bf16x8*)(Bs + lc * 64 + ((kc ^ (lc & 7)) << 3));
      }
#pragma unroll
      for (int rt = 0; rt < 4; ++rt)
#pragma unroll
        for (int ct = 0; ct < 4; ++ct)
          acc[rt][ct] = __builtin_amdgcn_mfma_f32_16x16x32_bf16(
              af[rt], bfr[ct], acc[rt][ct], 0, 0, 0);
    }
    __syncthreads();
  }
  // epilogue: C row = rb+wr+rt*16+(lane>>4)*4+r, col = cb+wc+ct*16+(lane&15)
  const int r0 = rb + wr + (lane >> 4) * 4;
  if (MODE == 1) {
#pragma unroll
    for (int ct = 0; ct < 4; ++ct) {
      const int col = cb + wc + ct * 16 + (lane & 15);
      const float bv = bias[col];
#pragma unroll
      for (int rt = 0; rt < 4; ++rt) {
        const int row = r0 + rt * 16;
#pragma unroll
        for (int r = 0; r < 4; ++r)
          outF[(size_t)(row + r) * 1024 + col] = acc[rt][ct][r] + bv;
      }
    }
  } else {
#pragma unroll
    for (int ct = 0; ct < 4; ++ct) {
      const int col = cb + wc + ct * 16 + (lane & 15);  // 0..3071
      const int part = col >> 10, rem = col & 1023;
      const int h = rem >> 6, d = rem & 63;
#pragma unroll
      for (int rt = 0; rt < 4; ++rt) {
        const int row = r0 + rt * 16;  // 0..8191
        const int bi = row >> 11, n = row & 2047;
        const size_t bh = (size_t)bi * 16 + h;
        if (part == 2) {  // V stored transposed: Vt[bh][d][n]
          bf16x4 pv;
#pragma unroll
          for (int r = 0; r < 4; ++r) pv[r] = (__bf16)acc[rt][ct][r];
          *(bf16x4*)(Vto + (bh * 64 + d) * 2048 + n) = pv;
        } else if (part == 0) {  // Q: [bh][n][d], pre-scaled by PSCALE
          __bf16* dst = Qo + (bh * 2048 + n) * 64 + d;
#pragma unroll
          for (int r = 0; r < 4; ++r)
            dst[(size_t)r * 64] = (__bf16)(acc[rt][ct][r] * PSCALE);
        } else {  // K: [bh][n][d]
          __bf16* dst = Ko + (bh * 2048 + n) * 64 + d;
#pragma unroll
          for (int r = 0; r < 4; ++r) dst[(size_t)r * 64] = (__bf16)acc[rt][ct][r];
        }
      }
    }
  }
}

// ------------- fused relu-attention: O = relu(Q' K^T) @ V  (Q' pre-scaled) --
// v4: K staged row-permuted so P-fragments feed K=32 PV MFMAs directly
// (halves PV matrix-pipe time vs 16x16x16); V consumed as conflict-free
// b128 B-fragments. 256-q blocks, 4 waves x 64 q, double-buffered tiles with
// counted vmcnt(8). grid (x=bh, y=qb): XCD = bh%8 -> per-XCD K/V set = 4MB.
__global__ __launch_bounds__(256) void attn_relu(
    const __bf16* __restrict__ Q, const __bf16* __restrict__ K,
    const __bf16* __restrict__ Vt, __bf16* __restrict__ O) {
  __shared__ __bf16 Ks[2][128 * 64];   // 2 x 16 KB
  __shared__ __bf16 Vs[2][64 * 128];   // 2 x 16 KB
  const int lane = threadIdx.x & 63, w = threadIdx.x >> 6;
  const int g = lane >> 4, c15 = lane & 15;
  const int bh = blockIdx.x, qb = blockIdx.y;
  const __bf16* Qg = Q + ((size_t)bh * 2048 + qb * 256) * 64;
  const __bf16* Kg = K + (size_t)bh * 2048 * 64;
  const __bf16* Vg = Vt + (size_t)bh * 64 * 2048;

  bf16x8 qf[4][2];  // wave's 64 q-rows as B-fragments (col=q=lane&15)
#pragma unroll
  for (int rt = 0; rt < 4; ++rt)
#pragma unroll
    for (int ks = 0; ks < 2; ++ks) {
      const int row = w * 64 + rt * 16 + c15;
      qf[rt][ks] = *(const bf16x8*)(Qg + row * 64 + ks * 32 + (g << 3));
    }
  f32x4 oacc[4][4] = {};

  // prologue: stage tile 0 into buffer 0 (8 gload_lds per thread per tile)
  stage_k_perm(Kg, Ks[0]);
  stage_vt(Vg, Vs[0]);

  for (int kb = 0; kb < 16; ++kb) {
    const int cur = kb & 1;
    if (kb < 15) {
      stage_k_perm(Kg + (size_t)(kb + 1) * 128 * 64, Ks[cur ^ 1]);
      stage_vt(Vg + (kb + 1) * 128, Vs[cur ^ 1]);
      // 16 outstanding (cur 8 + nxt 8) -> wait for the 8 oldest (= cur tile)
      asm volatile("s_waitcnt vmcnt(8)" ::: "memory");
    } else {
      asm volatile("s_waitcnt vmcnt(0)" ::: "memory");
    }
    __builtin_amdgcn_s_barrier();  // cur tile staged for all waves
    const __bf16* __restrict__ Kc = Ks[cur];
    const __bf16* __restrict__ Vc = Vs[cur];
#pragma unroll
    for (int u = 0; u < 4; ++u) {  // 32-key groups
      f32x4 sa[4] = {{}, {}, {}, {}}, sb[4] = {{}, {}, {}, {}};
      {
        const int kr = u * 32 + c15;  // LDS rows u*32..+15 (keys permuted)
        const bf16x8 kf0 =
            *(const bf16x8*)(Kc + kr * 64 + ((g ^ (kr & 7)) << 3));
        const bf16x8 kf1 =
            *(const bf16x8*)(Kc + kr * 64 + (((4 + g) ^ (kr & 7)) << 3));
#pragma unroll
        for (int rt = 0; rt < 4; ++rt) {
          sa[rt] = __builtin_amdgcn_mfma_f32_16x16x32_bf16(kf0, qf[rt][0],
                                                           sa[rt], 0, 0, 0);
          sa[rt] = __builtin_amdgcn_mfma_f32_16x16x32_bf16(kf1, qf[rt][1],
                                                           sa[rt], 0, 0, 0);
        }
      }
      {
        const int kr = u * 32 + 16 + c15;  // LDS rows u*32+16..+31
        const bf16x8 kf0 =
            *(const bf16x8*)(Kc + kr * 64 + ((g ^ (kr & 7)) << 3));
        const bf16x8 kf1 =
            *(const bf16x8*)(Kc + kr * 64 + (((4 + g) ^ (kr & 7)) << 3));
#pragma unroll
        for (int rt = 0; rt < 4; ++rt) {
          sb[rt] = __builtin_amdgcn_mfma_f32_16x16x32_bf16(kf0, qf[rt][0],
                                                           sb[rt], 0, 0, 0);
          sb[rt] = __builtin_amdgcn_mfma_f32_16x16x32_bf16(kf1, qf[rt][1],
                                                           sb[rt], 0, 0, 0);
        }
      }
      // relu -> bf16; lane holds P[q=c15][keys 32u+8g+0..7] = K=32 PV A-frag
      bf16x8 pa[4];
#pragma unroll
      for (int rt = 0; rt < 4; ++rt)
#pragma unroll
        for (int r = 0; r < 4; ++r) {
          pa[rt][r] = (__bf16)fmaxf(sa[rt][r], 0.0f);
          pa[rt][4 + r] = (__bf16)fmaxf(sb[rt][r], 0.0f);
        }
#pragma unroll
      for (int dt = 0; dt < 4; ++dt) {
        const int d = dt * 16 + c15;
        const bf16x8 vb = *(const bf16x8*)(
            Vc + d * 128 + (((4 * u + g) ^ c15) << 3));
#pragma unroll
        for (int rt = 0; rt < 4; ++rt)
          oacc[rt][dt] = __builtin_amdgcn_mfma_f32_16x16x32_bf16(
              pa[rt], vb, oacc[rt][dt], 0, 0, 0);
      }
    }
    __builtin_amdgcn_s_barrier();  // all waves done reading cur before restage
  }
  // write O merged-head: [b][n][h*64+d] bf16
  const int bi = bh >> 4, h = bh & 15;
#pragma unroll
  for (int rt = 0; rt < 4; ++rt)
#pragma unroll
    for (int dt = 0; dt < 4; ++dt) {
      const int col = h * 64 + dt * 16 + c15;
      const int n0 = qb * 256 + w * 64 + rt * 16 + g * 4;
      __bf16* dst = O + ((size_t)bi * 2048 + n0) * 1024 + col;
#pragma unroll
      for (int r = 0; r < 4; ++r) dst[(size_t)r * 1024] = (__bf16)oacc[rt][dt][r];
    }
}

extern "C" void kernel_launch(void* const* d_in, const int* in_sizes, int n_in,
                              void* d_out, int out_size, void* d_ws,
                              size_t ws_size, hipStream_t stream) {
  (void)in_sizes; (void)n_in; (void)out_size; (void)ws_size;
  const float* x = (const float*)d_in[0];
  const float* ln_w = (const float*)d_in[1];
  const float* ln_b = (const float*)d_in[2];
  const float* w_qkv = (const float*)d_in[3];
  const float* w_out = (const float*)d_in[4];
  const float* b_out = (const float*)d_in[5];
  // d_in[6] = layer_index == 2 (< DEPTH/2) -> relu branch only.
  char* ws = (char*)d_ws;
  __bf16* xn = (__bf16*)(ws);                           // 16 MB
  __bf16* Wt1 = (__bf16*)(ws + (size_t)(16u << 20));    // 6 MB  [3072][1024]
  __bf16* Wt2 = (__bf16*)(ws + (size_t)(22u << 20));    // 2 MB  [1024][1024]
  __bf16* Qb = (__bf16*)(ws + (size_t)(24u << 20));     // 16 MB [64][2048][64]
  __bf16* Kb = (__bf16*)(ws + (size_t)(40u << 20));     // 16 MB
  __bf16* Vtb = (__bf16*)(ws + (size_t)(56u << 20));    // 16 MB [64][64][2048]
  __bf16* Ob = (__bf16*)(ws + (size_t)(72u << 20));     // 16 MB [8192][1024]
  float* out = (float*)d_out;

  ln_fused<<<8192, 256, 0, stream>>>(x, ln_w, ln_b, xn);
  transpose_cvt<<<dim3(48, 16), 256, 0, stream>>>(w_qkv, Wt1, 1024, 3072);
  transpose_cvt<<<dim3(16, 16), 256, 0, stream>>>(w_out, Wt2, 1024, 1024);
  gemm_nt<0><<<dim3(24, 64), 256, 0, stream>>>(xn, Wt1, 1024, nullptr, Qb, Kb,
                                               Vtb, nullptr);
  attn_relu<<<dim3(64, 8), 256, 0, stream>>>(Qb, Kb, Vtb, Ob);
  gemm_nt<1><<<dim3(8, 64), 256, 0, stream>>>(Ob, Wt2, 1024, out, nullptr,
                                              nullptr, nullptr, b_out);
}

// Round 5
// 167.321 us; speedup vs baseline: 1.1344x; 1.0496x over previous
//
#include <hip/hip_runtime.h>
#include <stdint.h>

typedef __bf16 bf16x8 __attribute__((ext_vector_type(8)));
typedef __bf16 bf16x4 __attribute__((ext_vector_type(4)));
typedef float f32x4 __attribute__((ext_vector_type(4)));

#define PSCALE (0.125f / 2048.0f)

// async global->LDS, 16B per lane. LDS dest must be wave-uniform; HW adds lane*16.
#define GLOAD16(src, dst)                                                      \
  __builtin_amdgcn_global_load_lds(                                            \
      (__attribute__((address_space(1))) void*)const_cast<__bf16*>(src),       \
      (__attribute__((address_space(3))) void*)(dst), 16, 0, 0)

// ---------------- LayerNorm + cast to bf16 ----------------
__global__ __launch_bounds__(256) void ln_fused(const float* __restrict__ x,
                                                const float* __restrict__ w,
                                                const float* __restrict__ b,
                                                __bf16* __restrict__ xn) {
  const int row = blockIdx.x;           // 8192 rows
  const int t = threadIdx.x;            // 256 threads, 4 floats each
  const float4 v = ((const float4*)(x + (size_t)row * 1024))[t];
  float s = v.x + v.y + v.z + v.w;
  float ss = v.x * v.x + v.y * v.y + v.z * v.z + v.w * v.w;
#pragma unroll
  for (int o = 32; o; o >>= 1) {
    s += __shfl_down(s, o);
    ss += __shfl_down(ss, o);
  }
  __shared__ float red[8];
  if ((t & 63) == 0) {
    red[t >> 6] = s;
    red[4 + (t >> 6)] = ss;
  }
  __syncthreads();
  const float tot = red[0] + red[1] + red[2] + red[3];
  const float tot2 = red[4] + red[5] + red[6] + red[7];
  const float mu = tot * (1.0f / 1024.0f);
  const float var = tot2 * (1.0f / 1024.0f) - mu * mu;
  const float rs = rsqrtf(var + 1e-5f);
  const float4 wv = ((const float4*)w)[t];
  const float4 bv = ((const float4*)b)[t];
  bf16x4 o;
  o[0] = (__bf16)((v.x - mu) * rs * wv.x + bv.x);
  o[1] = (__bf16)((v.y - mu) * rs * wv.y + bv.y);
  o[2] = (__bf16)((v.z - mu) * rs * wv.z + bv.z);
  o[3] = (__bf16)((v.w - mu) * rs * wv.w + bv.w);
  ((bf16x4*)xn)[(size_t)row * 256 + t] = o;
}

// -------- transpose + fp32->bf16: A[R][C] -> At[C][R] (64x64 tiles) --------
__global__ __launch_bounds__(256) void transpose_cvt(const float* __restrict__ A,
                                                     __bf16* __restrict__ At,
                                                     int R, int C) {
  __shared__ __bf16 T[64][72];
  const int rb = blockIdx.y * 64, cb = blockIdx.x * 64;
  const int tid = threadIdx.x;
  const int r = tid >> 2, cg = tid & 3;
#pragma unroll
  for (int k = 0; k < 4; ++k) {
    const float4 v =
        *(const float4*)(A + (size_t)(rb + r) * C + cb + cg * 16 + k * 4);
    T[cg * 16 + k * 4 + 0][r] = (__bf16)v.x;
    T[cg * 16 + k * 4 + 1][r] = (__bf16)v.y;
    T[cg * 16 + k * 4 + 2][r] = (__bf16)v.z;
    T[cg * 16 + k * 4 + 3][r] = (__bf16)v.w;
  }
  __syncthreads();
#pragma unroll
  for (int i = 0; i < 2; ++i) {
    const int j = i * 256 + tid;
    const int c = j >> 3, s8 = j & 7;
    const bf16x8 o = *(const bf16x8*)&T[c][s8 * 8];
    *(bf16x8*)(At + (size_t)(cb + c) * R + rb + s8 * 8) = o;
  }
}

// ---- stage a [128 rows][64 k] bf16 tile into LDS, swizzled source (G4/rule21)
// LDS linear chunk j = row*8 + slot holds global k-chunk (slot ^ (row&7)).
__device__ __forceinline__ void stage_128x64(const __bf16* __restrict__ g,
                                             int ld, __bf16* lds) {
  const int lane = threadIdx.x & 63, w = threadIdx.x >> 6;
#pragma unroll
  for (int i = 0; i < 4; ++i) {
    const int j = i * 256 + w * 64 + lane;  // 1024 chunks of 16B
    const int row = j >> 3, slot = j & 7;
    const __bf16* src = g + (size_t)row * ld + ((slot ^ (row & 7)) << 3);
    GLOAD16(src, lds + (size_t)(i * 256 + w * 64) * 8);
  }
}

// ---------------- NT-GEMM: C[M][N] = A[M][K] * B[N][K]^T ----------------
// 128x128 tile, BK=64, 4 waves of 64x64. MODE 0: QKV split epilogue
// (Q pre-scaled by PSCALE so attn needs no per-element scaling).
// MODE 1: fp32 out + bias.
template <int MODE>
__global__ __launch_bounds__(256) void gemm_nt(
    const __bf16* __restrict__ A, const __bf16* __restrict__ B, int K,
    float* __restrict__ outF, __bf16* __restrict__ Qo, __bf16* __restrict__ Ko,
    __bf16* __restrict__ Vto, const float* __restrict__ bias) {
  __shared__ __bf16 As[128 * 64];
  __shared__ __bf16 Bs[128 * 64];
  const int lane = threadIdx.x & 63, w = threadIdx.x >> 6;
  const int rb = blockIdx.y * 128, cb = blockIdx.x * 128;
  const int wr = (w >> 1) * 64, wc = (w & 1) * 64;
  f32x4 acc[4][4] = {};
  const __bf16* Ab = A + (size_t)rb * K;
  const __bf16* Bb = B + (size_t)cb * K;
  const int nkb = K >> 6;
  for (int kb = 0; kb < nkb; ++kb) {
    stage_128x64(Ab + kb * 64, K, As);
    stage_128x64(Bb + kb * 64, K, Bs);
    __syncthreads();
#pragma unroll
    for (int ks = 0; ks < 2; ++ks) {
      bf16x8 af[4], bfr[4];
      const int kc = ks * 4 + (lane >> 4);
#pragma unroll
      for (int rt = 0; rt < 4; ++rt) {
        const int lr = wr + rt * 16 + (lane & 15);
        af[rt] = *(const bf16x8*)(As + lr * 64 + ((kc ^ (lr & 7)) << 3));
      }
#pragma unroll
      for (int ct = 0; ct < 4; ++ct) {
        const int lc = wc + ct * 16 + (lane & 15);
        bfr[ct] = *(const bf16x8*)(Bs + lc * 64 + ((kc ^ (lc & 7)) << 3));
      }
#pragma unroll
      for (int rt = 0; rt < 4; ++rt)
#pragma unroll
        for (int ct = 0; ct < 4; ++ct)
          acc[rt][ct] = __builtin_amdgcn_mfma_f32_16x16x32_bf16(
              af[rt], bfr[ct], acc[rt][ct], 0, 0, 0);
    }
    __syncthreads();
  }
  // epilogue: C row = rb+wr+rt*16+(lane>>4)*4+r, col = cb+wc+ct*16+(lane&15)
  const int r0 = rb + wr + (lane >> 4) * 4;
  if (MODE == 1) {
#pragma unroll
    for (int ct = 0; ct < 4; ++ct) {
      const int col = cb + wc + ct * 16 + (lane & 15);
      const float bv = bias[col];
#pragma unroll
      for (int rt = 0; rt < 4; ++rt) {
        const int row = r0 + rt * 16;
#pragma unroll
        for (int r = 0; r < 4; ++r)
          outF[(size_t)(row + r) * 1024 + col] = acc[rt][ct][r] + bv;
      }
    }
  } else {
#pragma unroll
    for (int ct = 0; ct < 4; ++ct) {
      const int col = cb + wc + ct * 16 + (lane & 15);  // 0..3071
      const int part = col >> 10, rem = col & 1023;
      const int h = rem >> 6, d = rem & 63;
#pragma unroll
      for (int rt = 0; rt < 4; ++rt) {
        const int row = r0 + rt * 16;  // 0..8191
        const int bi = row >> 11, n = row & 2047;
        const size_t bh = (size_t)bi * 16 + h;
        if (part == 2) {  // V stored transposed: Vt[bh][d][n]
          bf16x4 pv;
#pragma unroll
          for (int r = 0; r < 4; ++r) pv[r] = (__bf16)acc[rt][ct][r];
          *(bf16x4*)(Vto + (bh * 64 + d) * 2048 + n) = pv;
        } else if (part == 0) {  // Q: [bh][n][d], pre-scaled by PSCALE
          __bf16* dst = Qo + (bh * 2048 + n) * 64 + d;
#pragma unroll
          for (int r = 0; r < 4; ++r)
            dst[(size_t)r * 64] = (__bf16)(acc[rt][ct][r] * PSCALE);
        } else {  // K: [bh][n][d]
          __bf16* dst = Ko + (bh * 2048 + n) * 64 + d;
#pragma unroll
          for (int r = 0; r < 4; ++r) dst[(size_t)r * 64] = (__bf16)acc[rt][ct][r];
        }
      }
    }
  }
}

// ------------- fused relu-attention: O = relu(Q' K^T) @ V  (Q' pre-scaled) --
// v5: 512 threads / 8 waves per block, 32 q per wave -> 4 waves/SIMD (was 2)
// to overlap VALU/DS/MFMA across waves. K row-permuted in LDS so P feeds K=32
// PV MFMAs from registers; staging source addresses hoisted out of the kb
// loop (constant-stride pointer advance); setprio(1) around MFMA clusters
// (T5: counted-vmcnt structure has load-vs-MFMA wave role split).
// grid (x=bh, y=qb): XCD = bh%8 -> per-XCD K/V set = 4MB = its L2.
__global__ __launch_bounds__(512) void attn_relu(
    const __bf16* __restrict__ Q, const __bf16* __restrict__ K,
    const __bf16* __restrict__ Vt, __bf16* __restrict__ O) {
  __shared__ __bf16 Ks[2][128 * 64];   // 2 x 16 KB
  __shared__ __bf16 Vs[2][64 * 128];   // 2 x 16 KB
  const int tid = threadIdx.x;
  const int lane = tid & 63, w = tid >> 6;  // w: 0..7
  const int g = lane >> 4, c15 = lane & 15;
  const int bh = blockIdx.x, qb = blockIdx.y;
  const __bf16* Qg = Q + ((size_t)bh * 2048 + qb * 256) * 64;
  const __bf16* Kg = K + (size_t)bh * 2048 * 64;
  const __bf16* Vg = Vt + (size_t)bh * 64 * 2048;

  // hoisted per-thread staging sources (1024 16B chunks per tile, 512 thr):
  // K: LDS row holds global key kappa(row) (b4b3b2<-b3b2b4) + 3-bit XOR slot.
  // V: LDS chunk (d, slot) holds global key-chunk (slot ^ (d&15)).
  const __bf16* kp0;
  const __bf16* kp1;
  const __bf16* vp0;
  const __bf16* vp1;
  {
    const int j0 = tid, j1 = 512 + tid;
    const int r0_ = j0 >> 3, s0_ = j0 & 7;
    const int r1_ = j1 >> 3, s1_ = j1 & 7;
    const int sr0 = (r0_ & 96) | ((r0_ & 12) << 1) | ((r0_ & 16) >> 2) | (r0_ & 3);
    const int sr1 = (r1_ & 96) | ((r1_ & 12) << 1) | ((r1_ & 16) >> 2) | (r1_ & 3);
    kp0 = Kg + (size_t)sr0 * 64 + ((s0_ ^ (r0_ & 7)) << 3);
    kp1 = Kg + (size_t)sr1 * 64 + ((s1_ ^ (r1_ & 7)) << 3);
    const int d0_ = j0 >> 4, t0_ = j0 & 15;
    const int d1_ = j1 >> 4, t1_ = j1 & 15;
    vp0 = Vg + (size_t)d0_ * 2048 + ((t0_ ^ (d0_ & 15)) << 3);
    vp1 = Vg + (size_t)d1_ * 2048 + ((t1_ ^ (d1_ & 15)) << 3);
  }
  const int dstoff = w * 64 * 8;  // wave-uniform LDS chunk base (elements)

  bf16x8 qf[2][2];  // wave's 32 q-rows as B-fragments (col=q=lane&15)
#pragma unroll
  for (int rt = 0; rt < 2; ++rt)
#pragma unroll
    for (int ks = 0; ks < 2; ++ks) {
      const int row = w * 32 + rt * 16 + c15;
      qf[rt][ks] = *(const bf16x8*)(Qg + row * 64 + ks * 32 + (g << 3));
    }
  f32x4 oacc[2][4] = {};

  // prologue: stage tile 0 into buffer 0 (4 gload_lds per thread per tile)
  GLOAD16(kp0, Ks[0] + dstoff);
  GLOAD16(kp1, Ks[0] + 512 * 8 + dstoff);
  GLOAD16(vp0, Vs[0] + dstoff);
  GLOAD16(vp1, Vs[0] + 512 * 8 + dstoff);
  kp0 += 128 * 64; kp1 += 128 * 64; vp0 += 128; vp1 += 128;

  for (int kb = 0; kb < 16; ++kb) {
    const int cur = kb & 1;
    if (kb < 15) {
      GLOAD16(kp0, Ks[cur ^ 1] + dstoff);
      GLOAD16(kp1, Ks[cur ^ 1] + 512 * 8 + dstoff);
      GLOAD16(vp0, Vs[cur ^ 1] + dstoff);
      GLOAD16(vp1, Vs[cur ^ 1] + 512 * 8 + dstoff);
      kp0 += 128 * 64; kp1 += 128 * 64; vp0 += 128; vp1 += 128;
      // 8 outstanding (cur 4 + nxt 4) -> wait for the 4 oldest (= cur tile)
      asm volatile("s_waitcnt vmcnt(4)" ::: "memory");
    } else {
      asm volatile("s_waitcnt vmcnt(0)" ::: "memory");
    }
    __builtin_amdgcn_s_barrier();  // cur tile staged for all waves
    const __bf16* __restrict__ Kc = Ks[cur];
    const __bf16* __restrict__ Vc = Vs[cur];
#pragma unroll
    for (int u = 0; u < 4; ++u) {  // 32-key groups
      const int kra = u * 32 + c15;       // LDS rows u*32..+15 (keys permuted)
      const int krb = u * 32 + 16 + c15;  // LDS rows u*32+16..+31
      const bf16x8 kfa0 = *(const bf16x8*)(Kc + kra * 64 + ((g ^ (kra & 7)) << 3));
      const bf16x8 kfa1 = *(const bf16x8*)(Kc + kra * 64 + (((4 + g) ^ (kra & 7)) << 3));
      const bf16x8 kfb0 = *(const bf16x8*)(Kc + krb * 64 + ((g ^ (krb & 7)) << 3));
      const bf16x8 kfb1 = *(const bf16x8*)(Kc + krb * 64 + (((4 + g) ^ (krb & 7)) << 3));
      f32x4 sa[2] = {{}, {}}, sb[2] = {{}, {}};
      __builtin_amdgcn_s_setprio(1);
#pragma unroll
      for (int rt = 0; rt < 2; ++rt) {
        sa[rt] = __builtin_amdgcn_mfma_f32_16x16x32_bf16(kfa0, qf[rt][0], sa[rt], 0, 0, 0);
        sa[rt] = __builtin_amdgcn_mfma_f32_16x16x32_bf16(kfa1, qf[rt][1], sa[rt], 0, 0, 0);
        sb[rt] = __builtin_amdgcn_mfma_f32_16x16x32_bf16(kfb0, qf[rt][0], sb[rt], 0, 0, 0);
        sb[rt] = __builtin_amdgcn_mfma_f32_16x16x32_bf16(kfb1, qf[rt][1], sb[rt], 0, 0, 0);
      }
      __builtin_amdgcn_s_setprio(0);
      // relu -> bf16; lane holds P[q=c15][keys 32u+8g+0..7] = K=32 PV A-frag
      bf16x8 pa[2];
#pragma unroll
      for (int rt = 0; rt < 2; ++rt)
#pragma unroll
        for (int r = 0; r < 4; ++r) {
          pa[rt][r] = (__bf16)fmaxf(sa[rt][r], 0.0f);
          pa[rt][4 + r] = (__bf16)fmaxf(sb[rt][r], 0.0f);
        }
      __builtin_amdgcn_s_setprio(1);
#pragma unroll
      for (int dt = 0; dt < 4; ++dt) {
        const int d = dt * 16 + c15;
        const bf16x8 vb = *(const bf16x8*)(Vc + d * 128 + (((4 * u + g) ^ c15) << 3));
#pragma unroll
        for (int rt = 0; rt < 2; ++rt)
          oacc[rt][dt] = __builtin_amdgcn_mfma_f32_16x16x32_bf16(
              pa[rt], vb, oacc[rt][dt], 0, 0, 0);
      }
      __builtin_amdgcn_s_setprio(0);
    }
    __builtin_amdgcn_s_barrier();  // all waves done reading cur before restage
  }
  // write O merged-head: [b][n][h*64+d] bf16
  const int bi = bh >> 4, h = bh & 15;
#pragma unroll
  for (int rt = 0; rt < 2; ++rt)
#pragma unroll
    for (int dt = 0; dt < 4; ++dt) {
      const int col = h * 64 + dt * 16 + c15;
      const int n0 = qb * 256 + w * 32 + rt * 16 + g * 4;
      __bf16* dst = O + ((size_t)bi * 2048 + n0) * 1024 + col;
#pragma unroll
      for (int r = 0; r < 4; ++r) dst[(size_t)r * 1024] = (__bf16)oacc[rt][dt][r];
    }
}

extern "C" void kernel_launch(void* const* d_in, const int* in_sizes, int n_in,
                              void* d_out, int out_size, void* d_ws,
                              size_t ws_size, hipStream_t stream) {
  (void)in_sizes; (void)n_in; (void)out_size; (void)ws_size;
  const float* x = (const float*)d_in[0];
  const float* ln_w = (const float*)d_in[1];
  const float* ln_b = (const float*)d_in[2];
  const float* w_qkv = (const float*)d_in[3];
  const float* w_out = (const float*)d_in[4];
  const float* b_out = (const float*)d_in[5];
  // d_in[6] = layer_index == 2 (< DEPTH/2) -> relu branch only.
  char* ws = (char*)d_ws;
  __bf16* xn = (__bf16*)(ws);                           // 16 MB
  __bf16* Wt1 = (__bf16*)(ws + (size_t)(16u << 20));    // 6 MB  [3072][1024]
  __bf16* Wt2 = (__bf16*)(ws + (size_t)(22u << 20));    // 2 MB  [1024][1024]
  __bf16* Qb = (__bf16*)(ws + (size_t)(24u << 20));     // 16 MB [64][2048][64]
  __bf16* Kb = (__bf16*)(ws + (size_t)(40u << 20));     // 16 MB
  __bf16* Vtb = (__bf16*)(ws + (size_t)(56u << 20));    // 16 MB [64][64][2048]
  __bf16* Ob = (__bf16*)(ws + (size_t)(72u << 20));     // 16 MB [8192][1024]
  float* out = (float*)d_out;

  ln_fused<<<8192, 256, 0, stream>>>(x, ln_w, ln_b, xn);
  transpose_cvt<<<dim3(48, 16), 256, 0, stream>>>(w_qkv, Wt1, 1024, 3072);
  transpose_cvt<<<dim3(16, 16), 256, 0, stream>>>(w_out, Wt2, 1024, 1024);
  gemm_nt<0><<<dim3(24, 64), 256, 0, stream>>>(xn, Wt1, 1024, nullptr, Qb, Kb,
                                               Vtb, nullptr);
  attn_relu<<<dim3(64, 8), 512, 0, stream>>>(Qb, Kb, Vtb, Ob);
  gemm_nt<1><<<dim3(8, 64), 256, 0, stream>>>(Ob, Wt2, 1024, out, nullptr,
                                              nullptr, nullptr, b_out);
}

// Round 6
// 165.888 us; speedup vs baseline: 1.1442x; 1.0086x over previous
//
#include <hip/hip_runtime.h>
#include <stdint.h>

typedef __bf16 bf16x8 __attribute__((ext_vector_type(8)));
typedef __bf16 bf16x4 __attribute__((ext_vector_type(4)));
typedef float f32x4 __attribute__((ext_vector_type(4)));

#define PSCALE (0.125f / 2048.0f)

// async global->LDS, 16B per lane. LDS dest must be wave-uniform; HW adds lane*16.
#define GLOAD16(src, dst)                                                      \
  __builtin_amdgcn_global_load_lds(                                            \
      (__attribute__((address_space(1))) void*)const_cast<__bf16*>(src),       \
      (__attribute__((address_space(3))) void*)(dst), 16, 0, 0)

// ---------------- LayerNorm + cast to bf16 ----------------
__global__ __launch_bounds__(256) void ln_fused(const float* __restrict__ x,
                                                const float* __restrict__ w,
                                                const float* __restrict__ b,
                                                __bf16* __restrict__ xn) {
  const int row = blockIdx.x;           // 8192 rows
  const int t = threadIdx.x;            // 256 threads, 4 floats each
  const float4 v = ((const float4*)(x + (size_t)row * 1024))[t];
  float s = v.x + v.y + v.z + v.w;
  float ss = v.x * v.x + v.y * v.y + v.z * v.z + v.w * v.w;
#pragma unroll
  for (int o = 32; o; o >>= 1) {
    s += __shfl_down(s, o);
    ss += __shfl_down(ss, o);
  }
  __shared__ float red[8];
  if ((t & 63) == 0) {
    red[t >> 6] = s;
    red[4 + (t >> 6)] = ss;
  }
  __syncthreads();
  const float tot = red[0] + red[1] + red[2] + red[3];
  const float tot2 = red[4] + red[5] + red[6] + red[7];
  const float mu = tot * (1.0f / 1024.0f);
  const float var = tot2 * (1.0f / 1024.0f) - mu * mu;
  const float rs = rsqrtf(var + 1e-5f);
  const float4 wv = ((const float4*)w)[t];
  const float4 bv = ((const float4*)b)[t];
  bf16x4 o;
  o[0] = (__bf16)((v.x - mu) * rs * wv.x + bv.x);
  o[1] = (__bf16)((v.y - mu) * rs * wv.y + bv.y);
  o[2] = (__bf16)((v.z - mu) * rs * wv.z + bv.z);
  o[3] = (__bf16)((v.w - mu) * rs * wv.w + bv.w);
  ((bf16x4*)xn)[(size_t)row * 256 + t] = o;
}

// -------- transpose + fp32->bf16: A[R][C] -> At[C][R] (64x64 tiles) --------
__global__ __launch_bounds__(256) void transpose_cvt(const float* __restrict__ A,
                                                     __bf16* __restrict__ At,
                                                     int R, int C) {
  __shared__ __bf16 T[64][72];
  const int rb = blockIdx.y * 64, cb = blockIdx.x * 64;
  const int tid = threadIdx.x;
  const int r = tid >> 2, cg = tid & 3;
#pragma unroll
  for (int k = 0; k < 4; ++k) {
    const float4 v =
        *(const float4*)(A + (size_t)(rb + r) * C + cb + cg * 16 + k * 4);
    T[cg * 16 + k * 4 + 0][r] = (__bf16)v.x;
    T[cg * 16 + k * 4 + 1][r] = (__bf16)v.y;
    T[cg * 16 + k * 4 + 2][r] = (__bf16)v.z;
    T[cg * 16 + k * 4 + 3][r] = (__bf16)v.w;
  }
  __syncthreads();
#pragma unroll
  for (int i = 0; i < 2; ++i) {
    const int j = i * 256 + tid;
    const int c = j >> 3, s8 = j & 7;
    const bf16x8 o = *(const bf16x8*)&T[c][s8 * 8];
    *(bf16x8*)(At + (size_t)(cb + c) * R + rb + s8 * 8) = o;
  }
}

// ---------------- NT-GEMM v2: C[M][N] = A[M][K] * B[N][K]^T ----------------
// 128x256 tile, BK=64, 512 threads / 8 waves (2 row x 4 col), wave tile 64x64.
// 3-buffer LDS (144 KB), lead-2 staging with counted vmcnt(6):
//   iter u: vmcnt(6) [tile u landed; u+1's 6 loads stay in flight] -> barrier
//           -> issue tile u+2's 6 gload_lds into buf[(u+2)%3] -> ds_read+MFMA.
// Race audit: buf[(u+2)%3]'s previous tenant (u-1) was fully read before the
// start-of-u barrier (each wave's ds_reads retire before its MFMAs, which
// precede the barrier); the barrier also blocks fast waves from staging over
// slow readers. vmcnt is issue-ordered (m135).
// MODE 0: QKV split epilogue (Q pre-scaled by PSCALE). MODE 1: fp32 + bias.
template <int MODE>
__global__ __launch_bounds__(512) void gemm_nt(
    const __bf16* __restrict__ A, const __bf16* __restrict__ B, int K,
    float* __restrict__ outF, __bf16* __restrict__ Qo, __bf16* __restrict__ Ko,
    __bf16* __restrict__ Vto, const float* __restrict__ bias) {
  __shared__ __bf16 Sm[3 * 24576];  // per buf: A[128][64] @0, B[256][64] @8192
  const int tid = threadIdx.x;
  const int lane = tid & 63, w = tid >> 6;
  const int g = lane >> 4, c15 = lane & 15;
  const int wr = w >> 2, wc = w & 3;  // wave tile: rows wr*64, cols wc*64
  const int rb = blockIdx.y * 128, cb = blockIdx.x * 256;

  // hoisted staging sources: 6 chunks/thread/K-tile (2 A + 4 B), XOR-swizzled
  // source so LDS chunk (row, slot) holds k-chunk slot^(row&7) (rule 21).
  const __bf16* aSp[2];
  const __bf16* bSp[4];
  int aDo[2], bDo[4];
#pragma unroll
  for (int i = 0; i < 2; ++i) {
    const int j = i * 512 + tid, row = j >> 3, slot = j & 7;
    aSp[i] = A + (size_t)(rb + row) * K + ((slot ^ (row & 7)) << 3);
    aDo[i] = i * 4096 + w * 512;
  }
#pragma unroll
  for (int i = 0; i < 4; ++i) {
    const int j = i * 512 + tid, col = j >> 3, slot = j & 7;
    bSp[i] = B + (size_t)(cb + col) * K + ((slot ^ (col & 7)) << 3);
    bDo[i] = 8192 + i * 4096 + w * 512;
  }

  f32x4 acc[4][4] = {};
  const int nkb = K >> 6;  // 16

  // prologue: stage tiles 0,1 into bufs 0,1 (12 loads/thread outstanding)
#pragma unroll
  for (int t = 0; t < 2; ++t) {
    __bf16* dst = Sm + t * 24576;
#pragma unroll
    for (int i = 0; i < 2; ++i) GLOAD16(aSp[i] + t * 64, dst + aDo[i]);
#pragma unroll
    for (int i = 0; i < 4; ++i) GLOAD16(bSp[i] + t * 64, dst + bDo[i]);
  }

  int cur = 0, stg = 2, koff = 128;  // stage target tile = kb+2, k-offset
  for (int kb = 0; kb < nkb; ++kb) {
    if (kb == nkb - 1) {
      asm volatile("s_waitcnt vmcnt(0)" ::: "memory");
    } else {
      asm volatile("s_waitcnt vmcnt(6)" ::: "memory");
    }
    __builtin_amdgcn_s_barrier();  // tile kb staged & prior tenant reads done
    if (kb < nkb - 2) {
      __bf16* dst = Sm + stg * 24576;
#pragma unroll
      for (int i = 0; i < 2; ++i) GLOAD16(aSp[i] + koff, dst + aDo[i]);
#pragma unroll
      for (int i = 0; i < 4; ++i) GLOAD16(bSp[i] + koff, dst + bDo[i]);
      koff += 64;
    }
    const __bf16* __restrict__ Ac = Sm + cur * 24576;
    const __bf16* __restrict__ Bc = Ac + 8192;
#pragma unroll
    for (int ks = 0; ks < 2; ++ks) {
      bf16x8 af[4], bfr[4];
      const int kc = ks * 4 + g;
#pragma unroll
      for (int rt = 0; rt < 4; ++rt) {
        const int lr = wr * 64 + rt * 16 + c15;
        af[rt] = *(const bf16x8*)(Ac + lr * 64 + ((kc ^ (lr & 7)) << 3));
      }
#pragma unroll
      for (int ct = 0; ct < 4; ++ct) {
        const int lc = wc * 64 + ct * 16 + c15;
        bfr[ct] = *(const bf16x8*)(Bc + lc * 64 + ((kc ^ (lc & 7)) << 3));
      }
      __builtin_amdgcn_s_setprio(1);
#pragma unroll
      for (int rt = 0; rt < 4; ++rt)
#pragma unroll
        for (int ct = 0; ct < 4; ++ct)
          acc[rt][ct] = __builtin_amdgcn_mfma_f32_16x16x32_bf16(
              af[rt], bfr[ct], acc[rt][ct], 0, 0, 0);
      __builtin_amdgcn_s_setprio(0);
    }
    cur = (cur == 2) ? 0 : cur + 1;
    stg = (stg == 2) ? 0 : stg + 1;
  }
  // epilogue: C row = rb+wr*64+rt*16+g*4+r, col = cb+wc*64+ct*16+c15
  const int r00 = rb + wr * 64 + g * 4;
  if (MODE == 1) {
#pragma unroll
    for (int ct = 0; ct < 4; ++ct) {
      const int col = cb + wc * 64 + ct * 16 + c15;
      const float bv = bias[col];
#pragma unroll
      for (int rt = 0; rt < 4; ++rt) {
        const int row = r00 + rt * 16;
#pragma unroll
        for (int r = 0; r < 4; ++r)
          outF[(size_t)(row + r) * 1024 + col] = acc[rt][ct][r] + bv;
      }
    }
  } else {
#pragma unroll
    for (int ct = 0; ct < 4; ++ct) {
      const int col = cb + wc * 64 + ct * 16 + c15;  // 0..3071
      const int part = col >> 10, rem = col & 1023;
      const int h = rem >> 6, d = rem & 63;
#pragma unroll
      for (int rt = 0; rt < 4; ++rt) {
        const int row = r00 + rt * 16;  // 0..8191
        const int bi = row >> 11, n = row & 2047;
        const size_t bh = (size_t)bi * 16 + h;
        if (part == 2) {  // V stored transposed: Vt[bh][d][n]
          bf16x4 pv;
#pragma unroll
          for (int r = 0; r < 4; ++r) pv[r] = (__bf16)acc[rt][ct][r];
          *(bf16x4*)(Vto + (bh * 64 + d) * 2048 + n) = pv;
        } else if (part == 0) {  // Q: [bh][n][d], pre-scaled by PSCALE
          __bf16* dst = Qo + (bh * 2048 + n) * 64 + d;
#pragma unroll
          for (int r = 0; r < 4; ++r)
            dst[(size_t)r * 64] = (__bf16)(acc[rt][ct][r] * PSCALE);
        } else {  // K: [bh][n][d]
          __bf16* dst = Ko + (bh * 2048 + n) * 64 + d;
#pragma unroll
          for (int r = 0; r < 4; ++r) dst[(size_t)r * 64] = (__bf16)acc[rt][ct][r];
        }
      }
    }
  }
}

// ------------- fused relu-attention: O = relu(Q' K^T) @ V  (Q' pre-scaled) --
// v5 (unchanged): 512 threads / 8 waves, 32 q per wave, K row-permuted in LDS
// so P feeds K=32 PV MFMAs from registers; dbuf + counted vmcnt(4); setprio.
__global__ __launch_bounds__(512) void attn_relu(
    const __bf16* __restrict__ Q, const __bf16* __restrict__ K,
    const __bf16* __restrict__ Vt, __bf16* __restrict__ O) {
  __shared__ __bf16 Ks[2][128 * 64];   // 2 x 16 KB
  __shared__ __bf16 Vs[2][64 * 128];   // 2 x 16 KB
  const int tid = threadIdx.x;
  const int lane = tid & 63, w = tid >> 6;  // w: 0..7
  const int g = lane >> 4, c15 = lane & 15;
  const int bh = blockIdx.x, qb = blockIdx.y;
  const __bf16* Qg = Q + ((size_t)bh * 2048 + qb * 256) * 64;
  const __bf16* Kg = K + (size_t)bh * 2048 * 64;
  const __bf16* Vg = Vt + (size_t)bh * 64 * 2048;

  const __bf16* kp0;
  const __bf16* kp1;
  const __bf16* vp0;
  const __bf16* vp1;
  {
    const int j0 = tid, j1 = 512 + tid;
    const int r0_ = j0 >> 3, s0_ = j0 & 7;
    const int r1_ = j1 >> 3, s1_ = j1 & 7;
    const int sr0 = (r0_ & 96) | ((r0_ & 12) << 1) | ((r0_ & 16) >> 2) | (r0_ & 3);
    const int sr1 = (r1_ & 96) | ((r1_ & 12) << 1) | ((r1_ & 16) >> 2) | (r1_ & 3);
    kp0 = Kg + (size_t)sr0 * 64 + ((s0_ ^ (r0_ & 7)) << 3);
    kp1 = Kg + (size_t)sr1 * 64 + ((s1_ ^ (r1_ & 7)) << 3);
    const int d0_ = j0 >> 4, t0_ = j0 & 15;
    const int d1_ = j1 >> 4, t1_ = j1 & 15;
    vp0 = Vg + (size_t)d0_ * 2048 + ((t0_ ^ (d0_ & 15)) << 3);
    vp1 = Vg + (size_t)d1_ * 2048 + ((t1_ ^ (d1_ & 15)) << 3);
  }
  const int dstoff = w * 64 * 8;  // wave-uniform LDS chunk base (elements)

  bf16x8 qf[2][2];  // wave's 32 q-rows as B-fragments (col=q=lane&15)
#pragma unroll
  for (int rt = 0; rt < 2; ++rt)
#pragma unroll
    for (int ks = 0; ks < 2; ++ks) {
      const int row = w * 32 + rt * 16 + c15;
      qf[rt][ks] = *(const bf16x8*)(Qg + row * 64 + ks * 32 + (g << 3));
    }
  f32x4 oacc[2][4] = {};

  // prologue: stage tile 0 into buffer 0 (4 gload_lds per thread per tile)
  GLOAD16(kp0, Ks[0] + dstoff);
  GLOAD16(kp1, Ks[0] + 512 * 8 + dstoff);
  GLOAD16(vp0, Vs[0] + dstoff);
  GLOAD16(vp1, Vs[0] + 512 * 8 + dstoff);
  kp0 += 128 * 64; kp1 += 128 * 64; vp0 += 128; vp1 += 128;

  for (int kb = 0; kb < 16; ++kb) {
    const int cur = kb & 1;
    if (kb < 15) {
      GLOAD16(kp0, Ks[cur ^ 1] + dstoff);
      GLOAD16(kp1, Ks[cur ^ 1] + 512 * 8 + dstoff);
      GLOAD16(vp0, Vs[cur ^ 1] + dstoff);
      GLOAD16(vp1, Vs[cur ^ 1] + 512 * 8 + dstoff);
      kp0 += 128 * 64; kp1 += 128 * 64; vp0 += 128; vp1 += 128;
      // 8 outstanding (cur 4 + nxt 4) -> wait for the 4 oldest (= cur tile)
      asm volatile("s_waitcnt vmcnt(4)" ::: "memory");
    } else {
      asm volatile("s_waitcnt vmcnt(0)" ::: "memory");
    }
    __builtin_amdgcn_s_barrier();  // cur tile staged for all waves
    const __bf16* __restrict__ Kc = Ks[cur];
    const __bf16* __restrict__ Vc = Vs[cur];
#pragma unroll
    for (int u = 0; u < 4; ++u) {  // 32-key groups
      const int kra = u * 32 + c15;       // LDS rows u*32..+15 (keys permuted)
      const int krb = u * 32 + 16 + c15;  // LDS rows u*32+16..+31
      const bf16x8 kfa0 = *(const bf16x8*)(Kc + kra * 64 + ((g ^ (kra & 7)) << 3));
      const bf16x8 kfa1 = *(const bf16x8*)(Kc + kra * 64 + (((4 + g) ^ (kra & 7)) << 3));
      const bf16x8 kfb0 = *(const bf16x8*)(Kc + krb * 64 + ((g ^ (krb & 7)) << 3));
      const bf16x8 kfb1 = *(const bf16x8*)(Kc + krb * 64 + (((4 + g) ^ (krb & 7)) << 3));
      f32x4 sa[2] = {{}, {}}, sb[2] = {{}, {}};
      __builtin_amdgcn_s_setprio(1);
#pragma unroll
      for (int rt = 0; rt < 2; ++rt) {
        sa[rt] = __builtin_amdgcn_mfma_f32_16x16x32_bf16(kfa0, qf[rt][0], sa[rt], 0, 0, 0);
        sa[rt] = __builtin_amdgcn_mfma_f32_16x16x32_bf16(kfa1, qf[rt][1], sa[rt], 0, 0, 0);
        sb[rt] = __builtin_amdgcn_mfma_f32_16x16x32_bf16(kfb0, qf[rt][0], sb[rt], 0, 0, 0);
        sb[rt] = __builtin_amdgcn_mfma_f32_16x16x32_bf16(kfb1, qf[rt][1], sb[rt], 0, 0, 0);
      }
      __builtin_amdgcn_s_setprio(0);
      // relu -> bf16; lane holds P[q=c15][keys 32u+8g+0..7] = K=32 PV A-frag
      bf16x8 pa[2];
#pragma unroll
      for (int rt = 0; rt < 2; ++rt)
#pragma unroll
        for (int r = 0; r < 4; ++r) {
          pa[rt][r] = (__bf16)fmaxf(sa[rt][r], 0.0f);
          pa[rt][4 + r] = (__bf16)fmaxf(sb[rt][r], 0.0f);
        }
      __builtin_amdgcn_s_setprio(1);
#pragma unroll
      for (int dt = 0; dt < 4; ++dt) {
        const int d = dt * 16 + c15;
        const bf16x8 vb = *(const bf16x8*)(Vc + d * 128 + (((4 * u + g) ^ c15) << 3));
#pragma unroll
        for (int rt = 0; rt < 2; ++rt)
          oacc[rt][dt] = __builtin_amdgcn_mfma_f32_16x16x32_bf16(
              pa[rt], vb, oacc[rt][dt], 0, 0, 0);
      }
      __builtin_amdgcn_s_setprio(0);
    }
    __builtin_amdgcn_s_barrier();  // all waves done reading cur before restage
  }
  // write O merged-head: [b][n][h*64+d] bf16
  const int bi = bh >> 4, h = bh & 15;
#pragma unroll
  for (int rt = 0; rt < 2; ++rt)
#pragma unroll
    for (int dt = 0; dt < 4; ++dt) {
      const int col = h * 64 + dt * 16 + c15;
      const int n0 = qb * 256 + w * 32 + rt * 16 + g * 4;
      __bf16* dst = O + ((size_t)bi * 2048 + n0) * 1024 + col;
#pragma unroll
      for (int r = 0; r < 4; ++r) dst[(size_t)r * 1024] = (__bf16)oacc[rt][dt][r];
    }
}

extern "C" void kernel_launch(void* const* d_in, const int* in_sizes, int n_in,
                              void* d_out, int out_size, void* d_ws,
                              size_t ws_size, hipStream_t stream) {
  (void)in_sizes; (void)n_in; (void)out_size; (void)ws_size;
  const float* x = (const float*)d_in[0];
  const float* ln_w = (const float*)d_in[1];
  const float* ln_b = (const float*)d_in[2];
  const float* w_qkv = (const float*)d_in[3];
  const float* w_out = (const float*)d_in[4];
  const float* b_out = (const float*)d_in[5];
  // d_in[6] = layer_index == 2 (< DEPTH/2) -> relu branch only.
  char* ws = (char*)d_ws;
  __bf16* xn = (__bf16*)(ws);                           // 16 MB
  __bf16* Wt1 = (__bf16*)(ws + (size_t)(16u << 20));    // 6 MB  [3072][1024]
  __bf16* Wt2 = (__bf16*)(ws + (size_t)(22u << 20));    // 2 MB  [1024][1024]
  __bf16* Qb = (__bf16*)(ws + (size_t)(24u << 20));     // 16 MB [64][2048][64]
  __bf16* Kb = (__bf16*)(ws + (size_t)(40u << 20));     // 16 MB
  __bf16* Vtb = (__bf16*)(ws + (size_t)(56u << 20));    // 16 MB [64][64][2048]
  __bf16* Ob = (__bf16*)(ws + (size_t)(72u << 20));     // 16 MB [8192][1024]
  float* out = (float*)d_out;

  ln_fused<<<8192, 256, 0, stream>>>(x, ln_w, ln_b, xn);
  transpose_cvt<<<dim3(48, 16), 256, 0, stream>>>(w_qkv, Wt1, 1024, 3072);
  transpose_cvt<<<dim3(16, 16), 256, 0, stream>>>(w_out, Wt2, 1024, 1024);
  gemm_nt<0><<<dim3(12, 64), 512, 0, stream>>>(xn, Wt1, 1024, nullptr, Qb, Kb,
                                               Vtb, nullptr);
  attn_relu<<<dim3(64, 8), 512, 0, stream>>>(Qb, Kb, Vtb, Ob);
  gemm_nt<1><<<dim3(4, 64), 512, 0, stream>>>(Ob, Wt2, 1024, out, nullptr,
                                              nullptr, nullptr, b_out);
}

// Round 7
// 159.410 us; speedup vs baseline: 1.1907x; 1.0406x over previous
//
#include <hip/hip_runtime.h>
#include <stdint.h>

typedef __bf16 bf16x8 __attribute__((ext_vector_type(8)));
typedef __bf16 bf16x4 __attribute__((ext_vector_type(4)));
typedef float f32x4 __attribute__((ext_vector_type(4)));

#define PSCALE (0.125f / 2048.0f)

// async global->LDS, 16B per lane. LDS dest must be wave-uniform; HW adds lane*16.
#define GLOAD16(src, dst)                                                      \
  __builtin_amdgcn_global_load_lds(                                            \
      (__attribute__((address_space(1))) void*)const_cast<__bf16*>(src),       \
      (__attribute__((address_space(3))) void*)(dst), 16, 0, 0)

// -------- prep: LayerNorm (blocks 0..8191) + w_qkv transpose (8192..8959)
//          + w_out transpose (8960..9215), all fp32 -> bf16 ----------------
__global__ __launch_bounds__(256) void prep(
    const float* __restrict__ x, const float* __restrict__ lw,
    const float* __restrict__ lb, __bf16* __restrict__ xn,
    const float* __restrict__ w_qkv, __bf16* __restrict__ Wt1,
    const float* __restrict__ w_out, __bf16* __restrict__ Wt2) {
  __shared__ __bf16 T[64][72];
  __shared__ float red[8];
  const int b = blockIdx.x;
  const int t = threadIdx.x;
  if (b < 8192) {  // ---- LayerNorm row b ----
    const float4 v = ((const float4*)(x + (size_t)b * 1024))[t];
    float s = v.x + v.y + v.z + v.w;
    float ss = v.x * v.x + v.y * v.y + v.z * v.z + v.w * v.w;
#pragma unroll
    for (int o = 32; o; o >>= 1) {
      s += __shfl_down(s, o);
      ss += __shfl_down(ss, o);
    }
    if ((t & 63) == 0) {
      red[t >> 6] = s;
      red[4 + (t >> 6)] = ss;
    }
    __syncthreads();
    const float tot = red[0] + red[1] + red[2] + red[3];
    const float tot2 = red[4] + red[5] + red[6] + red[7];
    const float mu = tot * (1.0f / 1024.0f);
    const float var = tot2 * (1.0f / 1024.0f) - mu * mu;
    const float rs = rsqrtf(var + 1e-5f);
    const float4 wv = ((const float4*)lw)[t];
    const float4 bv = ((const float4*)lb)[t];
    bf16x4 o;
    o[0] = (__bf16)((v.x - mu) * rs * wv.x + bv.x);
    o[1] = (__bf16)((v.y - mu) * rs * wv.y + bv.y);
    o[2] = (__bf16)((v.z - mu) * rs * wv.z + bv.z);
    o[3] = (__bf16)((v.w - mu) * rs * wv.w + bv.w);
    ((bf16x4*)xn)[(size_t)b * 256 + t] = o;
    return;
  }
  // ---- transpose+cvt 64x64 tile: A[R][C] -> At[C][R] ----
  const float* A;
  __bf16* At;
  int R, C, bx, by;
  if (b < 8960) {
    const int ti = b - 8192;           // 768 tiles: 48 x 16
    A = w_qkv; At = Wt1; R = 1024; C = 3072;
    bx = ti % 48; by = ti / 48;
  } else {
    const int ti = b - 8960;           // 256 tiles: 16 x 16
    A = w_out; At = Wt2; R = 1024; C = 1024;
    bx = ti % 16; by = ti / 16;
  }
  const int rb = by * 64, cb = bx * 64;
  const int r = t >> 2, cg = t & 3;
#pragma unroll
  for (int k = 0; k < 4; ++k) {
    const float4 v =
        *(const float4*)(A + (size_t)(rb + r) * C + cb + cg * 16 + k * 4);
    T[cg * 16 + k * 4 + 0][r] = (__bf16)v.x;
    T[cg * 16 + k * 4 + 1][r] = (__bf16)v.y;
    T[cg * 16 + k * 4 + 2][r] = (__bf16)v.z;
    T[cg * 16 + k * 4 + 3][r] = (__bf16)v.w;
  }
  __syncthreads();
#pragma unroll
  for (int i = 0; i < 2; ++i) {
    const int j = i * 256 + t;
    const int c = j >> 3, s8 = j & 7;
    const bf16x8 o = *(const bf16x8*)&T[c][s8 * 8];
    *(bf16x8*)(At + (size_t)(cb + c) * R + rb + s8 * 8) = o;
  }
}

// ---------------- NT-GEMM v2: C[M][N] = A[M][K] * B[N][K]^T ----------------
// 128x256 tile, BK=64, 512 threads / 8 waves (2 row x 4 col), wave tile 64x64.
// 3-buffer LDS (144 KB), lead-2 staging with counted vmcnt(6); staging issue
// split around the ks=0 MFMA block so VMEM issue overlaps MFMA.
// XCD-chunked block remap (nwg%8==0): each XCD gets nwg/8 consecutive tiles
// -> its 8 row-panels' A working set (2 MB) fits the per-XCD L2.
// Race audit (unchanged from R6): buf[(u+2)%3]'s previous tenant (u-1) was
// fully read before the start-of-u barrier; all 6 stage-issues for u+2 happen
// between that barrier and the end of u's compute, so the top-of-(u+1)
// vmcnt(6) waits exactly for tile u+1's 6 loads. vmcnt is issue-ordered.
// MODE 0: QKV split epilogue (Q pre-scaled by PSCALE). MODE 1: fp32 + bias.
template <int MODE>
__global__ __launch_bounds__(512) void gemm_nt(
    const __bf16* __restrict__ A, const __bf16* __restrict__ B, int K,
    float* __restrict__ outF, __bf16* __restrict__ Qo, __bf16* __restrict__ Ko,
    __bf16* __restrict__ Vto, const float* __restrict__ bias) {
  __shared__ __bf16 Sm[3 * 24576];  // per buf: A[128][64] @0, B[256][64] @8192
  const int tid = threadIdx.x;
  const int lane = tid & 63, w = tid >> 6;
  const int g = lane >> 4, c15 = lane & 15;
  const int wr = w >> 2, wc = w & 3;  // wave tile: rows wr*64, cols wc*64
  // XCD-chunked bijective remap (gridDim.x*gridDim.y % 8 == 0)
  const int linear = blockIdx.y * gridDim.x + blockIdx.x;
  const int per = (gridDim.x * gridDim.y) >> 3;
  const int nl = (linear & 7) * per + (linear >> 3);
  const int rb = (nl / gridDim.x) * 128, cb = (nl % gridDim.x) * 256;

  // hoisted staging sources: 6 chunks/thread/K-tile (2 A + 4 B), XOR-swizzled
  // source so LDS chunk (row, slot) holds k-chunk slot^(row&7) (rule 21).
  const __bf16* aSp[2];
  const __bf16* bSp[4];
  int aDo[2], bDo[4];
#pragma unroll
  for (int i = 0; i < 2; ++i) {
    const int j = i * 512 + tid, row = j >> 3, slot = j & 7;
    aSp[i] = A + (size_t)(rb + row) * K + ((slot ^ (row & 7)) << 3);
    aDo[i] = i * 4096 + w * 512;
  }
#pragma unroll
  for (int i = 0; i < 4; ++i) {
    const int j = i * 512 + tid, col = j >> 3, slot = j & 7;
    bSp[i] = B + (size_t)(cb + col) * K + ((slot ^ (col & 7)) << 3);
    bDo[i] = 8192 + i * 4096 + w * 512;
  }

  f32x4 acc[4][4] = {};
  const int nkb = K >> 6;  // 16

  // prologue: stage tiles 0,1 into bufs 0,1 (12 loads/thread outstanding)
#pragma unroll
  for (int t = 0; t < 2; ++t) {
    __bf16* dst = Sm + t * 24576;
#pragma unroll
    for (int i = 0; i < 2; ++i) GLOAD16(aSp[i] + t * 64, dst + aDo[i]);
#pragma unroll
    for (int i = 0; i < 4; ++i) GLOAD16(bSp[i] + t * 64, dst + bDo[i]);
  }

  int cur = 0, stg = 2, koff = 128;  // stage target tile = kb+2, k-offset
  for (int kb = 0; kb < nkb; ++kb) {
    if (kb == nkb - 1) {
      asm volatile("s_waitcnt vmcnt(0)" ::: "memory");
    } else {
      asm volatile("s_waitcnt vmcnt(6)" ::: "memory");
    }
    __builtin_amdgcn_s_barrier();  // tile kb staged & prior tenant reads done
    const bool do_stage = (kb < nkb - 2);
    __bf16* sdst = Sm + stg * 24576;
    if (do_stage) {
#pragma unroll
      for (int i = 0; i < 2; ++i) GLOAD16(aSp[i] + koff, sdst + aDo[i]);
    }
    const __bf16* __restrict__ Ac = Sm + cur * 24576;
    const __bf16* __restrict__ Bc = Ac + 8192;
    // ks = 0
    {
      bf16x8 af[4], bfr[4];
      const int kc = g;
#pragma unroll
      for (int rt = 0; rt < 4; ++rt) {
        const int lr = wr * 64 + rt * 16 + c15;
        af[rt] = *(const bf16x8*)(Ac + lr * 64 + ((kc ^ (lr & 7)) << 3));
      }
#pragma unroll
      for (int ct = 0; ct < 4; ++ct) {
        const int lc = wc * 64 + ct * 16 + c15;
        bfr[ct] = *(const bf16x8*)(Bc + lc * 64 + ((kc ^ (lc & 7)) << 3));
      }
      __builtin_amdgcn_s_setprio(1);
#pragma unroll
      for (int rt = 0; rt < 4; ++rt)
#pragma unroll
        for (int ct = 0; ct < 4; ++ct)
          acc[rt][ct] = __builtin_amdgcn_mfma_f32_16x16x32_bf16(
              af[rt], bfr[ct], acc[rt][ct], 0, 0, 0);
      __builtin_amdgcn_s_setprio(0);
    }
    if (do_stage) {
#pragma unroll
      for (int i = 0; i < 4; ++i) GLOAD16(bSp[i] + koff, sdst + bDo[i]);
      koff += 64;
    }
    // ks = 1
    {
      bf16x8 af[4], bfr[4];
      const int kc = 4 + g;
#pragma unroll
      for (int rt = 0; rt < 4; ++rt) {
        const int lr = wr * 64 + rt * 16 + c15;
        af[rt] = *(const bf16x8*)(Ac + lr * 64 + ((kc ^ (lr & 7)) << 3));
      }
#pragma unroll
      for (int ct = 0; ct < 4; ++ct) {
        const int lc = wc * 64 + ct * 16 + c15;
        bfr[ct] = *(const bf16x8*)(Bc + lc * 64 + ((kc ^ (lc & 7)) << 3));
      }
      __builtin_amdgcn_s_setprio(1);
#pragma unroll
      for (int rt = 0; rt < 4; ++rt)
#pragma unroll
        for (int ct = 0; ct < 4; ++ct)
          acc[rt][ct] = __builtin_amdgcn_mfma_f32_16x16x32_bf16(
              af[rt], bfr[ct], acc[rt][ct], 0, 0, 0);
      __builtin_amdgcn_s_setprio(0);
    }
    cur = (cur == 2) ? 0 : cur + 1;
    stg = (stg == 2) ? 0 : stg + 1;
  }
  // epilogue: C row = rb+wr*64+rt*16+g*4+r, col = cb+wc*64+ct*16+c15
  const int r00 = rb + wr * 64 + g * 4;
  if (MODE == 1) {
#pragma unroll
    for (int ct = 0; ct < 4; ++ct) {
      const int col = cb + wc * 64 + ct * 16 + c15;
      const float bv = bias[col];
#pragma unroll
      for (int rt = 0; rt < 4; ++rt) {
        const int row = r00 + rt * 16;
#pragma unroll
        for (int r = 0; r < 4; ++r)
          outF[(size_t)(row + r) * 1024 + col] = acc[rt][ct][r] + bv;
      }
    }
  } else {
#pragma unroll
    for (int ct = 0; ct < 4; ++ct) {
      const int col = cb + wc * 64 + ct * 16 + c15;  // 0..3071
      const int part = col >> 10, rem = col & 1023;
      const int h = rem >> 6, d = rem & 63;
#pragma unroll
      for (int rt = 0; rt < 4; ++rt) {
        const int row = r00 + rt * 16;  // 0..8191
        const int bi = row >> 11, n = row & 2047;
        const size_t bh = (size_t)bi * 16 + h;
        if (part == 2) {  // V stored transposed: Vt[bh][d][n]
          bf16x4 pv;
#pragma unroll
          for (int r = 0; r < 4; ++r) pv[r] = (__bf16)acc[rt][ct][r];
          *(bf16x4*)(Vto + (bh * 64 + d) * 2048 + n) = pv;
        } else if (part == 0) {  // Q: [bh][n][d], pre-scaled by PSCALE
          __bf16* dst = Qo + (bh * 2048 + n) * 64 + d;
#pragma unroll
          for (int r = 0; r < 4; ++r)
            dst[(size_t)r * 64] = (__bf16)(acc[rt][ct][r] * PSCALE);
        } else {  // K: [bh][n][d]
          __bf16* dst = Ko + (bh * 2048 + n) * 64 + d;
#pragma unroll
          for (int r = 0; r < 4; ++r) dst[(size_t)r * 64] = (__bf16)acc[rt][ct][r];
        }
      }
    }
  }
}

// ------------- fused relu-attention: O = relu(Q' K^T) @ V  (Q' pre-scaled) --
// v5 (unchanged): 512 threads / 8 waves, 32 q per wave, K row-permuted in LDS
// so P feeds K=32 PV MFMAs from registers; dbuf + counted vmcnt(4); setprio.
__global__ __launch_bounds__(512) void attn_relu(
    const __bf16* __restrict__ Q, const __bf16* __restrict__ K,
    const __bf16* __restrict__ Vt, __bf16* __restrict__ O) {
  __shared__ __bf16 Ks[2][128 * 64];   // 2 x 16 KB
  __shared__ __bf16 Vs[2][64 * 128];   // 2 x 16 KB
  const int tid = threadIdx.x;
  const int lane = tid & 63, w = tid >> 6;  // w: 0..7
  const int g = lane >> 4, c15 = lane & 15;
  const int bh = blockIdx.x, qb = blockIdx.y;
  const __bf16* Qg = Q + ((size_t)bh * 2048 + qb * 256) * 64;
  const __bf16* Kg = K + (size_t)bh * 2048 * 64;
  const __bf16* Vg = Vt + (size_t)bh * 64 * 2048;

  const __bf16* kp0;
  const __bf16* kp1;
  const __bf16* vp0;
  const __bf16* vp1;
  {
    const int j0 = tid, j1 = 512 + tid;
    const int r0_ = j0 >> 3, s0_ = j0 & 7;
    const int r1_ = j1 >> 3, s1_ = j1 & 7;
    const int sr0 = (r0_ & 96) | ((r0_ & 12) << 1) | ((r0_ & 16) >> 2) | (r0_ & 3);
    const int sr1 = (r1_ & 96) | ((r1_ & 12) << 1) | ((r1_ & 16) >> 2) | (r1_ & 3);
    kp0 = Kg + (size_t)sr0 * 64 + ((s0_ ^ (r0_ & 7)) << 3);
    kp1 = Kg + (size_t)sr1 * 64 + ((s1_ ^ (r1_ & 7)) << 3);
    const int d0_ = j0 >> 4, t0_ = j0 & 15;
    const int d1_ = j1 >> 4, t1_ = j1 & 15;
    vp0 = Vg + (size_t)d0_ * 2048 + ((t0_ ^ (d0_ & 15)) << 3);
    vp1 = Vg + (size_t)d1_ * 2048 + ((t1_ ^ (d1_ & 15)) << 3);
  }
  const int dstoff = w * 64 * 8;  // wave-uniform LDS chunk base (elements)

  bf16x8 qf[2][2];  // wave's 32 q-rows as B-fragments (col=q=lane&15)
#pragma unroll
  for (int rt = 0; rt < 2; ++rt)
#pragma unroll
    for (int ks = 0; ks < 2; ++ks) {
      const int row = w * 32 + rt * 16 + c15;
      qf[rt][ks] = *(const bf16x8*)(Qg + row * 64 + ks * 32 + (g << 3));
    }
  f32x4 oacc[2][4] = {};

  // prologue: stage tile 0 into buffer 0 (4 gload_lds per thread per tile)
  GLOAD16(kp0, Ks[0] + dstoff);
  GLOAD16(kp1, Ks[0] + 512 * 8 + dstoff);
  GLOAD16(vp0, Vs[0] + dstoff);
  GLOAD16(vp1, Vs[0] + 512 * 8 + dstoff);
  kp0 += 128 * 64; kp1 += 128 * 64; vp0 += 128; vp1 += 128;

  for (int kb = 0; kb < 16; ++kb) {
    const int cur = kb & 1;
    if (kb < 15) {
      GLOAD16(kp0, Ks[cur ^ 1] + dstoff);
      GLOAD16(kp1, Ks[cur ^ 1] + 512 * 8 + dstoff);
      GLOAD16(vp0, Vs[cur ^ 1] + dstoff);
      GLOAD16(vp1, Vs[cur ^ 1] + 512 * 8 + dstoff);
      kp0 += 128 * 64; kp1 += 128 * 64; vp0 += 128; vp1 += 128;
      // 8 outstanding (cur 4 + nxt 4) -> wait for the 4 oldest (= cur tile)
      asm volatile("s_waitcnt vmcnt(4)" ::: "memory");
    } else {
      asm volatile("s_waitcnt vmcnt(0)" ::: "memory");
    }
    __builtin_amdgcn_s_barrier();  // cur tile staged for all waves
    const __bf16* __restrict__ Kc = Ks[cur];
    const __bf16* __restrict__ Vc = Vs[cur];
#pragma unroll
    for (int u = 0; u < 4; ++u) {  // 32-key groups
      const int kra = u * 32 + c15;       // LDS rows u*32..+15 (keys permuted)
      const int krb = u * 32 + 16 + c15;  // LDS rows u*32+16..+31
      const bf16x8 kfa0 = *(const bf16x8*)(Kc + kra * 64 + ((g ^ (kra & 7)) << 3));
      const bf16x8 kfa1 = *(const bf16x8*)(Kc + kra * 64 + (((4 + g) ^ (kra & 7)) << 3));
      const bf16x8 kfb0 = *(const bf16x8*)(Kc + krb * 64 + ((g ^ (krb & 7)) << 3));
      const bf16x8 kfb1 = *(const bf16x8*)(Kc + krb * 64 + (((4 + g) ^ (krb & 7)) << 3));
      f32x4 sa[2] = {{}, {}}, sb[2] = {{}, {}};
      __builtin_amdgcn_s_setprio(1);
#pragma unroll
      for (int rt = 0; rt < 2; ++rt) {
        sa[rt] = __builtin_amdgcn_mfma_f32_16x16x32_bf16(kfa0, qf[rt][0], sa[rt], 0, 0, 0);
        sa[rt] = __builtin_amdgcn_mfma_f32_16x16x32_bf16(kfa1, qf[rt][1], sa[rt], 0, 0, 0);
        sb[rt] = __builtin_amdgcn_mfma_f32_16x16x32_bf16(kfb0, qf[rt][0], sb[rt], 0, 0, 0);
        sb[rt] = __builtin_amdgcn_mfma_f32_16x16x32_bf16(kfb1, qf[rt][1], sb[rt], 0, 0, 0);
      }
      __builtin_amdgcn_s_setprio(0);
      // relu -> bf16; lane holds P[q=c15][keys 32u+8g+0..7] = K=32 PV A-frag
      bf16x8 pa[2];
#pragma unroll
      for (int rt = 0; rt < 2; ++rt)
#pragma unroll
        for (int r = 0; r < 4; ++r) {
          pa[rt][r] = (__bf16)fmaxf(sa[rt][r], 0.0f);
          pa[rt][4 + r] = (__bf16)fmaxf(sb[rt][r], 0.0f);
        }
      __builtin_amdgcn_s_setprio(1);
#pragma unroll
      for (int dt = 0; dt < 4; ++dt) {
        const int d = dt * 16 + c15;
        const bf16x8 vb = *(const bf16x8*)(Vc + d * 128 + (((4 * u + g) ^ c15) << 3));
#pragma unroll
        for (int rt = 0; rt < 2; ++rt)
          oacc[rt][dt] = __builtin_amdgcn_mfma_f32_16x16x32_bf16(
              pa[rt], vb, oacc[rt][dt], 0, 0, 0);
      }
      __builtin_amdgcn_s_setprio(0);
    }
    __builtin_amdgcn_s_barrier();  // all waves done reading cur before restage
  }
  // write O merged-head: [b][n][h*64+d] bf16
  const int bi = bh >> 4, h = bh & 15;
#pragma unroll
  for (int rt = 0; rt < 2; ++rt)
#pragma unroll
    for (int dt = 0; dt < 4; ++dt) {
      const int col = h * 64 + dt * 16 + c15;
      const int n0 = qb * 256 + w * 32 + rt * 16 + g * 4;
      __bf16* dst = O + ((size_t)bi * 2048 + n0) * 1024 + col;
#pragma unroll
      for (int r = 0; r < 4; ++r) dst[(size_t)r * 1024] = (__bf16)oacc[rt][dt][r];
    }
}

extern "C" void kernel_launch(void* const* d_in, const int* in_sizes, int n_in,
                              void* d_out, int out_size, void* d_ws,
                              size_t ws_size, hipStream_t stream) {
  (void)in_sizes; (void)n_in; (void)out_size; (void)ws_size;
  const float* x = (const float*)d_in[0];
  const float* ln_w = (const float*)d_in[1];
  const float* ln_b = (const float*)d_in[2];
  const float* w_qkv = (const float*)d_in[3];
  const float* w_out = (const float*)d_in[4];
  const float* b_out = (const float*)d_in[5];
  // d_in[6] = layer_index == 2 (< DEPTH/2) -> relu branch only.
  char* ws = (char*)d_ws;
  __bf16* xn = (__bf16*)(ws);                           // 16 MB
  __bf16* Wt1 = (__bf16*)(ws + (size_t)(16u << 20));    // 6 MB  [3072][1024]
  __bf16* Wt2 = (__bf16*)(ws + (size_t)(22u << 20));    // 2 MB  [1024][1024]
  __bf16* Qb = (__bf16*)(ws + (size_t)(24u << 20));     // 16 MB [64][2048][64]
  __bf16* Kb = (__bf16*)(ws + (size_t)(40u << 20));     // 16 MB
  __bf16* Vtb = (__bf16*)(ws + (size_t)(56u << 20));    // 16 MB [64][64][2048]
  __bf16* Ob = (__bf16*)(ws + (size_t)(72u << 20));     // 16 MB [8192][1024]
  float* out = (float*)d_out;

  prep<<<9216, 256, 0, stream>>>(x, ln_w, ln_b, xn, w_qkv, Wt1, w_out, Wt2);
  gemm_nt<0><<<dim3(12, 64), 512, 0, stream>>>(xn, Wt1, 1024, nullptr, Qb, Kb,
                                               Vtb, nullptr);
  attn_relu<<<dim3(64, 8), 512, 0, stream>>>(Qb, Kb, Vtb, Ob);
  gemm_nt<1><<<dim3(4, 64), 512, 0, stream>>>(Ob, Wt2, 1024, out, nullptr,
                                              nullptr, nullptr, b_out);
}